// Round 1
// baseline (8226.877 us; speedup 1.0000x reference)
//
#include <hip/hip_runtime.h>
#include <hip/hip_bf16.h>
#include <math.h>

#define NEG_SLOPE 0.2f

__device__ __forceinline__ float lrelu(float x) { return x > 0.f ? x : NEG_SLOPE * x; }

// monotone float->uint encoding for atomicMax on floats (incl. negatives)
__device__ __forceinline__ unsigned int fenc(float f) {
    unsigned int u = __float_as_uint(f);
    return (u & 0x80000000u) ? ~u : (u | 0x80000000u);
}
__device__ __forceinline__ float fdec(unsigned int u) {
    return __uint_as_float((u & 0x80000000u) ? (u & 0x7fffffffu) : ~u);
}

// ---------------------------------------------------------------------------
// init: zero [num1|denom1|num2|denom2], set m1/m2 to enc(-inf)
// ---------------------------------------------------------------------------
__global__ __launch_bounds__(256) void k_init(float* __restrict__ zb, long nz4,
                                              unsigned int* __restrict__ m1, long n1,
                                              unsigned int* __restrict__ m2, long n2) {
    long i = (long)blockIdx.x * 256 + threadIdx.x;
    long stride = (long)gridDim.x * 256;
    float4 z = make_float4(0.f, 0.f, 0.f, 0.f);
    for (long j = i; j < nz4; j += stride) ((float4*)zb)[j] = z;
    for (long j = i; j < n1; j += stride) m1[j] = 0x007FFFFFu;  // enc(-inf)
    for (long j = i; j < n2; j += stride) m2[j] = 0x007FFFFFu;
}

// ---------------------------------------------------------------------------
// GEMM1: h1 = x @ W1  ([N,128]@[128,128]), fused a_src1/a_dst1 epilogue.
// Tile: 16 rows x 128 cols per block (256 thr). W1 fully in LDS (64KB).
// Thread t: row = t>>4, cols [ (t&15)*8 , +8 ).
// ---------------------------------------------------------------------------
__global__ __launch_bounds__(256) void k_gemm1(const float* __restrict__ x,
                                               const float* __restrict__ W,
                                               const float* __restrict__ att_s,
                                               const float* __restrict__ att_d,
                                               float* __restrict__ h1,
                                               float* __restrict__ a_src,
                                               float* __restrict__ a_dst, int N) {
    __shared__ float Ws[128 * 128];   // 64 KB
    __shared__ float xs[16 * 132];    // padded stride 132 (bank spread), 8.25KB
    int t = threadIdx.x;
    for (int i = t * 4; i < 128 * 128; i += 256 * 4)
        *(float4*)&Ws[i] = *(const float4*)&W[i];
    int row0 = blockIdx.x * 16;
    for (int idx = t; idx < 16 * 32; idx += 256) {
        int r = idx >> 5, c4 = (idx & 31) * 4;
        int g = row0 + r;
        float4 v = make_float4(0.f, 0.f, 0.f, 0.f);
        if (g < N) v = *(const float4*)&x[(size_t)g * 128 + c4];
        *(float4*)&xs[r * 132 + c4] = v;
    }
    __syncthreads();

    int r = t >> 4;
    int col0 = (t & 15) * 8;
    int g = row0 + r;
    float acc[8] = {0.f, 0.f, 0.f, 0.f, 0.f, 0.f, 0.f, 0.f};
#pragma unroll 8
    for (int k = 0; k < 128; ++k) {
        float xv = xs[r * 132 + k];
        float4 w0 = *(const float4*)&Ws[k * 128 + col0];
        float4 w1 = *(const float4*)&Ws[k * 128 + col0 + 4];
        acc[0] = fmaf(xv, w0.x, acc[0]);
        acc[1] = fmaf(xv, w0.y, acc[1]);
        acc[2] = fmaf(xv, w0.z, acc[2]);
        acc[3] = fmaf(xv, w0.w, acc[3]);
        acc[4] = fmaf(xv, w1.x, acc[4]);
        acc[5] = fmaf(xv, w1.y, acc[5]);
        acc[6] = fmaf(xv, w1.z, acc[6]);
        acc[7] = fmaf(xv, w1.w, acc[7]);
    }
    if (g < N) {
        *(float4*)&h1[(size_t)g * 128 + col0]     = make_float4(acc[0], acc[1], acc[2], acc[3]);
        *(float4*)&h1[(size_t)g * 128 + col0 + 4] = make_float4(acc[4], acc[5], acc[6], acc[7]);
        float ps = 0.f, pd = 0.f;
#pragma unroll
        for (int j = 0; j < 8; ++j) {
            ps = fmaf(acc[j], att_s[col0 + j], ps);
            pd = fmaf(acc[j], att_d[col0 + j], pd);
        }
        // threads t and t^1 share a head (16 cols): pair-reduce in-wave
        ps += __shfl_xor(ps, 1);
        pd += __shfl_xor(pd, 1);
        if ((t & 1) == 0) {
            int head = (t & 15) >> 1;
            a_src[(size_t)g * 8 + head] = ps;
            a_dst[(size_t)g * 8 + head] = pd;
        }
    }
}

// ---------------------------------------------------------------------------
// Layer-1 edge passes
// ---------------------------------------------------------------------------
__global__ __launch_bounds__(256) void k_edge_max1(const int* __restrict__ ei, int E, int N,
                                                   const float* __restrict__ a_src,
                                                   const float* __restrict__ a_dst,
                                                   unsigned int* __restrict__ m1) {
    int e = blockIdx.x * 256 + threadIdx.x;
    if (e >= E + N) return;
    int s, d;
    if (e < E) { s = ei[e]; d = ei[E + e]; } else { s = d = e - E; }
    float4 as0 = *(const float4*)&a_src[(size_t)s * 8];
    float4 as1 = *(const float4*)&a_src[(size_t)s * 8 + 4];
    float4 ad0 = *(const float4*)&a_dst[(size_t)d * 8];
    float4 ad1 = *(const float4*)&a_dst[(size_t)d * 8 + 4];
    float al[8] = {as0.x + ad0.x, as0.y + ad0.y, as0.z + ad0.z, as0.w + ad0.w,
                   as1.x + ad1.x, as1.y + ad1.y, as1.z + ad1.z, as1.w + ad1.w};
#pragma unroll
    for (int h = 0; h < 8; ++h)
        atomicMax(&m1[(size_t)d * 8 + h], fenc(lrelu(al[h])));
}

__global__ __launch_bounds__(256) void k_edge_acc1(const int* __restrict__ ei, int E, int N,
                                                   const float* __restrict__ a_src,
                                                   const float* __restrict__ a_dst,
                                                   const unsigned int* __restrict__ m1,
                                                   const float* __restrict__ h1,
                                                   float* __restrict__ denom1,
                                                   float* __restrict__ num1) {
    int e = blockIdx.x * 256 + threadIdx.x;
    if (e >= E + N) return;
    int s, d;
    if (e < E) { s = ei[e]; d = ei[E + e]; } else { s = d = e - E; }
    float4 as0 = *(const float4*)&a_src[(size_t)s * 8];
    float4 as1 = *(const float4*)&a_src[(size_t)s * 8 + 4];
    float4 ad0 = *(const float4*)&a_dst[(size_t)d * 8];
    float4 ad1 = *(const float4*)&a_dst[(size_t)d * 8 + 4];
    uint4 m0 = *(const uint4*)&m1[(size_t)d * 8];
    uint4 m4 = *(const uint4*)&m1[(size_t)d * 8 + 4];
    float al[8] = {as0.x + ad0.x, as0.y + ad0.y, as0.z + ad0.z, as0.w + ad0.w,
                   as1.x + ad1.x, as1.y + ad1.y, as1.z + ad1.z, as1.w + ad1.w};
    float mm[8] = {fdec(m0.x), fdec(m0.y), fdec(m0.z), fdec(m0.w),
                   fdec(m4.x), fdec(m4.y), fdec(m4.z), fdec(m4.w)};
    float eh[8];
#pragma unroll
    for (int h = 0; h < 8; ++h) eh[h] = __expf(lrelu(al[h]) - mm[h]);
#pragma unroll
    for (int h = 0; h < 8; ++h) atomicAdd(&denom1[(size_t)d * 8 + h], eh[h]);
#pragma unroll
    for (int h = 0; h < 8; ++h) {
        float w = eh[h];
#pragma unroll
        for (int c0 = 0; c0 < 16; c0 += 4) {
            float4 hv = *(const float4*)&h1[(size_t)s * 128 + h * 16 + c0];
            atomicAdd(&num1[(size_t)d * 128 + h * 16 + c0 + 0], w * hv.x);
            atomicAdd(&num1[(size_t)d * 128 + h * 16 + c0 + 1], w * hv.y);
            atomicAdd(&num1[(size_t)d * 128 + h * 16 + c0 + 2], w * hv.z);
            atomicAdd(&num1[(size_t)d * 128 + h * 16 + c0 + 3], w * hv.w);
        }
    }
}

// ---------------------------------------------------------------------------
// GEMM2: h2 = out1 @ W2, where out1 = num1/denom1 + bias1 computed inline.
// One row per thread; W2 (20.5KB) + bias1 in LDS. Fused a_src2/a_dst2.
// ---------------------------------------------------------------------------
__global__ __launch_bounds__(256) void k_gemm2(const float* __restrict__ num1,
                                               const float* __restrict__ denom1,
                                               const float* __restrict__ bias1,
                                               const float* __restrict__ W2,
                                               const float* __restrict__ att_s2,
                                               const float* __restrict__ att_d2,
                                               float* __restrict__ h2,
                                               float* __restrict__ a_src2,
                                               float* __restrict__ a_dst2, int N) {
    __shared__ float Ws[128 * 40];
    __shared__ float bs[128];
    int t = threadIdx.x;
    for (int i = t * 4; i < 128 * 40; i += 256 * 4)
        *(float4*)&Ws[i] = *(const float4*)&W2[i];
    if (t < 32) *(float4*)&bs[t * 4] = *(const float4*)&bias1[t * 4];
    __syncthreads();
    int n = blockIdx.x * 256 + t;
    if (n >= N) return;

    float dn[8];
    {
        float4 d0 = *(const float4*)&denom1[(size_t)n * 8];
        float4 d1 = *(const float4*)&denom1[(size_t)n * 8 + 4];
        dn[0] = d0.x; dn[1] = d0.y; dn[2] = d0.z; dn[3] = d0.w;
        dn[4] = d1.x; dn[5] = d1.y; dn[6] = d1.z; dn[7] = d1.w;
    }
    float inv[8];
#pragma unroll
    for (int h = 0; h < 8; ++h) inv[h] = 1.f / (dn[h] + 1e-16f);

    float acc[40];
#pragma unroll
    for (int c = 0; c < 40; ++c) acc[c] = 0.f;

    for (int k0 = 0; k0 < 128; k0 += 4) {
        float4 v = *(const float4*)&num1[(size_t)n * 128 + k0];
        float xj[4] = {v.x, v.y, v.z, v.w};
        float iv = inv[k0 >> 4];  // k0..k0+3 within one head (C=16)
#pragma unroll
        for (int j = 0; j < 4; ++j) {
            float xb = fmaf(xj[j], iv, bs[k0 + j]);
#pragma unroll
            for (int c0 = 0; c0 < 40; c0 += 4) {
                float4 w = *(const float4*)&Ws[(k0 + j) * 40 + c0];
                acc[c0 + 0] = fmaf(xb, w.x, acc[c0 + 0]);
                acc[c0 + 1] = fmaf(xb, w.y, acc[c0 + 1]);
                acc[c0 + 2] = fmaf(xb, w.z, acc[c0 + 2]);
                acc[c0 + 3] = fmaf(xb, w.w, acc[c0 + 3]);
            }
        }
    }
    float s2 = 0.f, d2 = 0.f;
#pragma unroll
    for (int c = 0; c < 40; ++c) {
        s2 = fmaf(acc[c], att_s2[c], s2);
        d2 = fmaf(acc[c], att_d2[c], d2);
    }
#pragma unroll
    for (int c0 = 0; c0 < 40; c0 += 4)
        *(float4*)&h2[(size_t)n * 40 + c0] = make_float4(acc[c0], acc[c0 + 1], acc[c0 + 2], acc[c0 + 3]);
    a_src2[n] = s2;
    a_dst2[n] = d2;
}

// ---------------------------------------------------------------------------
// Layer-2 edge passes (H=1, C=40)
// ---------------------------------------------------------------------------
__global__ __launch_bounds__(256) void k_edge_max2(const int* __restrict__ ei, int E, int N,
                                                   const float* __restrict__ a_src,
                                                   const float* __restrict__ a_dst,
                                                   unsigned int* __restrict__ m2) {
    int e = blockIdx.x * 256 + threadIdx.x;
    if (e >= E + N) return;
    int s, d;
    if (e < E) { s = ei[e]; d = ei[E + e]; } else { s = d = e - E; }
    float al = lrelu(a_src[s] + a_dst[d]);
    atomicMax(&m2[d], fenc(al));
}

__global__ __launch_bounds__(256) void k_edge_acc2(const int* __restrict__ ei, int E, int N,
                                                   const float* __restrict__ a_src,
                                                   const float* __restrict__ a_dst,
                                                   const unsigned int* __restrict__ m2,
                                                   const float* __restrict__ h2,
                                                   float* __restrict__ denom2,
                                                   float* __restrict__ num2) {
    int e = blockIdx.x * 256 + threadIdx.x;
    if (e >= E + N) return;
    int s, d;
    if (e < E) { s = ei[e]; d = ei[E + e]; } else { s = d = e - E; }
    float al = lrelu(a_src[s] + a_dst[d]);
    float ev = __expf(al - fdec(m2[d]));
    atomicAdd(&denom2[d], ev);
#pragma unroll
    for (int c0 = 0; c0 < 40; c0 += 4) {
        float4 hv = *(const float4*)&h2[(size_t)s * 40 + c0];
        atomicAdd(&num2[(size_t)d * 40 + c0 + 0], ev * hv.x);
        atomicAdd(&num2[(size_t)d * 40 + c0 + 1], ev * hv.y);
        atomicAdd(&num2[(size_t)d * 40 + c0 + 2], ev * hv.z);
        atomicAdd(&num2[(size_t)d * 40 + c0 + 3], ev * hv.w);
    }
}

__global__ __launch_bounds__(256) void k_fin2(const float* __restrict__ num2,
                                              const float* __restrict__ denom2,
                                              const float* __restrict__ bias2,
                                              float* __restrict__ out, int N) {
    int i = blockIdx.x * 256 + threadIdx.x;
    if (i >= N * 40) return;
    int n = i / 40, c = i % 40;
    out[i] = num2[i] / (denom2[n] + 1e-16f) + bias2[c];
}

// ---------------------------------------------------------------------------
extern "C" void kernel_launch(void* const* d_in, const int* in_sizes, int n_in,
                              void* d_out, int out_size, void* d_ws, size_t ws_size,
                              hipStream_t stream) {
    const float* x   = (const float*)d_in[0];
    const int*   ei  = (const int*)d_in[1];   // JAX default x64-off -> int32
    const float* W1  = (const float*)d_in[2];
    const float* as1 = (const float*)d_in[3];
    const float* ad1 = (const float*)d_in[4];
    const float* b1  = (const float*)d_in[5];
    const float* W2  = (const float*)d_in[6];
    const float* as2 = (const float*)d_in[7];
    const float* ad2 = (const float*)d_in[8];
    const float* b2  = (const float*)d_in[9];

    int N = in_sizes[0] / 128;
    int E = in_sizes[1] / 2;
    size_t Np = (size_t)((N + 3) & ~3);

    float* ws = (float*)d_ws;
    float* h1      = ws; ws += Np * 128;
    float* num1    = ws; ws += Np * 128;   // zero region start
    float* denom1  = ws; ws += Np * 8;
    float* num2    = ws; ws += Np * 40;
    float* denom2  = ws; ws += Np;         // zero region end
    float* a_src1  = ws; ws += Np * 8;
    float* a_dst1  = ws; ws += Np * 8;
    float* a_src2v = ws; ws += Np;
    float* a_dst2v = ws; ws += Np;
    float* h2      = ws; ws += Np * 40;
    unsigned int* m1 = (unsigned int*)ws; ws += Np * 8;
    unsigned int* m2 = (unsigned int*)ws; ws += Np;

    long nz4 = (long)Np * (128 + 8 + 40 + 1) / 4;
    k_init<<<2048, 256, 0, stream>>>(num1, nz4, m1, (long)N * 8, m2, (long)N);

    int EN = E + N;
    k_gemm1<<<(N + 15) / 16, 256, 0, stream>>>(x, W1, as1, ad1, h1, a_src1, a_dst1, N);
    k_edge_max1<<<(EN + 255) / 256, 256, 0, stream>>>(ei, E, N, a_src1, a_dst1, m1);
    k_edge_acc1<<<(EN + 255) / 256, 256, 0, stream>>>(ei, E, N, a_src1, a_dst1, m1, h1, denom1, num1);
    k_gemm2<<<(N + 255) / 256, 256, 0, stream>>>(num1, denom1, b1, W2, as2, ad2, h2, a_src2v, a_dst2v, N);
    k_edge_max2<<<(EN + 255) / 256, 256, 0, stream>>>(ei, E, N, a_src2v, a_dst2v, m2);
    k_edge_acc2<<<(EN + 255) / 256, 256, 0, stream>>>(ei, E, N, a_src2v, a_dst2v, m2, h2, denom2, num2);
    k_fin2<<<((long)N * 40 + 255) / 256, 256, 0, stream>>>(num2, denom2, b2, (float*)d_out, N);
}

// Round 2
// 516.344 us; speedup vs baseline: 15.9329x; 15.9329x over previous
//
#include <hip/hip_runtime.h>
#include <hip/hip_bf16.h>
#include <math.h>

#define NEG_SLOPE 0.2f

__device__ __forceinline__ float lrelu(float x) { return x > 0.f ? x : NEG_SLOPE * x; }

// ---------------------------------------------------------------------------
// init: zero cnt + cursor (int)
// ---------------------------------------------------------------------------
__global__ __launch_bounds__(256) void k_init(int* __restrict__ cnt, int* __restrict__ cur, int N) {
    int i = blockIdx.x * 256 + threadIdx.x;
    int stride = gridDim.x * 256;
    for (int j = i; j < N; j += stride) { cnt[j] = 0; cur[j] = 0; }
}

// ---------------------------------------------------------------------------
// histogram of dst (incl. self-loops)
// ---------------------------------------------------------------------------
__global__ __launch_bounds__(256) void k_hist(const int* __restrict__ ei, int E, int N,
                                              int* __restrict__ cnt) {
    int e = blockIdx.x * 256 + threadIdx.x;
    if (e >= E + N) return;
    int d = (e < E) ? ei[E + e] : (e - E);
    atomicAdd(&cnt[d], 1);
}

// ---------------------------------------------------------------------------
// 3-stage exclusive scan of cnt[N] -> rowptr[N]; chunk = 1024 per block
// ---------------------------------------------------------------------------
__global__ __launch_bounds__(256) void k_scan_part(const int* __restrict__ cnt, int N,
                                                   int* __restrict__ psum) {
    __shared__ int sh[256];
    int t = threadIdx.x;
    int base = blockIdx.x * 1024 + t * 4;
    int tl = 0;
#pragma unroll
    for (int j = 0; j < 4; ++j) tl += (base + j < N) ? cnt[base + j] : 0;
    sh[t] = tl; __syncthreads();
    for (int off = 128; off > 0; off >>= 1) {
        if (t < off) sh[t] += sh[t + off];
        __syncthreads();
    }
    if (t == 0) psum[blockIdx.x] = sh[0];
}

__global__ __launch_bounds__(256) void k_scan_mid(int* __restrict__ psum, int nb) {
    __shared__ int sh[256];
    int t = threadIdx.x;
    int v = (t < nb) ? psum[t] : 0;
    sh[t] = v; __syncthreads();
    for (int off = 1; off < 256; off <<= 1) {
        int a = (t >= off) ? sh[t - off] : 0;
        __syncthreads();
        sh[t] += a;
        __syncthreads();
    }
    psum[t] = sh[t] - v;  // exclusive
}

__global__ __launch_bounds__(256) void k_scan_add(const int* __restrict__ cnt, int N,
                                                  const int* __restrict__ psum,
                                                  int* __restrict__ rowptr) {
    __shared__ int sh[256];
    int t = threadIdx.x;
    int base = blockIdx.x * 1024 + t * 4;
    int c[4]; int tl = 0;
#pragma unroll
    for (int j = 0; j < 4; ++j) { c[j] = (base + j < N) ? cnt[base + j] : 0; tl += c[j]; }
    sh[t] = tl; __syncthreads();
    for (int off = 1; off < 256; off <<= 1) {
        int a = (t >= off) ? sh[t - off] : 0;
        __syncthreads();
        sh[t] += a;
        __syncthreads();
    }
    int run = psum[blockIdx.x] + (sh[t] - tl);
#pragma unroll
    for (int j = 0; j < 4; ++j) {
        if (base + j < N) { rowptr[base + j] = run; run += c[j]; }
    }
}

// ---------------------------------------------------------------------------
// scatter src into CSR by dst
// ---------------------------------------------------------------------------
__global__ __launch_bounds__(256) void k_scatter(const int* __restrict__ ei, int E, int N,
                                                 const int* __restrict__ rowptr,
                                                 int* __restrict__ cur,
                                                 int* __restrict__ col) {
    int e = blockIdx.x * 256 + threadIdx.x;
    if (e >= E + N) return;
    int s, d;
    if (e < E) { s = ei[e]; d = ei[E + e]; } else { s = d = e - E; }
    int pos = rowptr[d] + atomicAdd(&cur[d], 1);
    col[pos] = s;
}

// ---------------------------------------------------------------------------
// GEMM1: h1 = x @ W1  ([N,128]@[128,128]), fused a_src1/a_dst1 epilogue.
// ---------------------------------------------------------------------------
__global__ __launch_bounds__(256) void k_gemm1(const float* __restrict__ x,
                                               const float* __restrict__ W,
                                               const float* __restrict__ att_s,
                                               const float* __restrict__ att_d,
                                               float* __restrict__ h1,
                                               float* __restrict__ a_src,
                                               float* __restrict__ a_dst, int N) {
    __shared__ float Ws[128 * 128];   // 64 KB
    __shared__ float xs[16 * 132];
    int t = threadIdx.x;
    for (int i = t * 4; i < 128 * 128; i += 256 * 4)
        *(float4*)&Ws[i] = *(const float4*)&W[i];
    int row0 = blockIdx.x * 16;
    for (int idx = t; idx < 16 * 32; idx += 256) {
        int r = idx >> 5, c4 = (idx & 31) * 4;
        int g = row0 + r;
        float4 v = make_float4(0.f, 0.f, 0.f, 0.f);
        if (g < N) v = *(const float4*)&x[(size_t)g * 128 + c4];
        *(float4*)&xs[r * 132 + c4] = v;
    }
    __syncthreads();

    int r = t >> 4;
    int col0 = (t & 15) * 8;
    int g = row0 + r;
    float acc[8] = {0.f, 0.f, 0.f, 0.f, 0.f, 0.f, 0.f, 0.f};
#pragma unroll 8
    for (int k = 0; k < 128; ++k) {
        float xv = xs[r * 132 + k];
        float4 w0 = *(const float4*)&Ws[k * 128 + col0];
        float4 w1 = *(const float4*)&Ws[k * 128 + col0 + 4];
        acc[0] = fmaf(xv, w0.x, acc[0]);
        acc[1] = fmaf(xv, w0.y, acc[1]);
        acc[2] = fmaf(xv, w0.z, acc[2]);
        acc[3] = fmaf(xv, w0.w, acc[3]);
        acc[4] = fmaf(xv, w1.x, acc[4]);
        acc[5] = fmaf(xv, w1.y, acc[5]);
        acc[6] = fmaf(xv, w1.z, acc[6]);
        acc[7] = fmaf(xv, w1.w, acc[7]);
    }
    if (g < N) {
        *(float4*)&h1[(size_t)g * 128 + col0]     = make_float4(acc[0], acc[1], acc[2], acc[3]);
        *(float4*)&h1[(size_t)g * 128 + col0 + 4] = make_float4(acc[4], acc[5], acc[6], acc[7]);
        float ps = 0.f, pd = 0.f;
#pragma unroll
        for (int j = 0; j < 8; ++j) {
            ps = fmaf(acc[j], att_s[col0 + j], ps);
            pd = fmaf(acc[j], att_d[col0 + j], pd);
        }
        ps += __shfl_xor(ps, 1);
        pd += __shfl_xor(pd, 1);
        if ((t & 1) == 0) {
            int head = (t & 15) >> 1;
            a_src[(size_t)g * 8 + head] = ps;
            a_dst[(size_t)g * 8 + head] = pd;
        }
    }
}

// ---------------------------------------------------------------------------
// Layer-1 aggregation: one wave per dst node. Lane l owns channels 2l,2l+1
// (head = l>>3). Two passes over CSR edges: max, then exp-accumulate.
// Writes finalized out1 = num/denom + bias1.
// ---------------------------------------------------------------------------
__global__ __launch_bounds__(256) void k_aggr1(const int* __restrict__ rowptr,
                                               const int* __restrict__ cnt,
                                               const int* __restrict__ col,
                                               const float* __restrict__ a_src,
                                               const float* __restrict__ a_dst,
                                               const float* __restrict__ h1,
                                               const float* __restrict__ bias1,
                                               float* __restrict__ out1, int N) {
    int t = threadIdx.x;
    int node = blockIdx.x * 4 + (t >> 6);
    int lane = t & 63;
    if (node >= N) return;
    int beg = rowptr[node];
    int deg = cnt[node];
    int h = lane >> 3;
    float adh = a_dst[(size_t)node * 8 + h];

    // pass A: max
    float m = -3.402823466e38f;
    int s = col[beg];
    for (int i = 0; i < deg; ++i) {
        int sn = (i + 1 < deg) ? col[beg + i + 1] : s;  // prefetch
        float v = lrelu(a_src[(size_t)s * 8 + h] + adh);
        m = fmaxf(m, v);
        s = sn;
    }
    // pass B: accumulate
    float den = 0.f, n0 = 0.f, n1 = 0.f;
    s = col[beg];
    for (int i = 0; i < deg; ++i) {
        int sn = (i + 1 < deg) ? col[beg + i + 1] : s;
        float v = lrelu(a_src[(size_t)s * 8 + h] + adh);
        float ev = __expf(v - m);
        den += ev;
        float2 hv = *(const float2*)&h1[(size_t)s * 128 + 2 * lane];
        n0 = fmaf(ev, hv.x, n0);
        n1 = fmaf(ev, hv.y, n1);
        s = sn;
    }
    float inv = 1.f / (den + 1e-16f);
    float2 b = *(const float2*)&bias1[2 * lane];
    float2 o = make_float2(fmaf(n0, inv, b.x), fmaf(n1, inv, b.y));
    *(float2*)&out1[(size_t)node * 128 + 2 * lane] = o;
}

// ---------------------------------------------------------------------------
// GEMM2: h2 = out1 @ W2  ([N,128]@[128,40]); fused a_src2/a_dst2 epilogue.
// ---------------------------------------------------------------------------
__global__ __launch_bounds__(256) void k_gemm2(const float* __restrict__ out1,
                                               const float* __restrict__ W2,
                                               const float* __restrict__ att_s2,
                                               const float* __restrict__ att_d2,
                                               float* __restrict__ h2,
                                               float* __restrict__ a_src2,
                                               float* __restrict__ a_dst2, int N) {
    __shared__ float Ws[128 * 40];
    int t = threadIdx.x;
    for (int i = t * 4; i < 128 * 40; i += 256 * 4)
        *(float4*)&Ws[i] = *(const float4*)&W2[i];
    __syncthreads();
    int n = blockIdx.x * 256 + t;
    if (n >= N) return;

    float acc[40];
#pragma unroll
    for (int c = 0; c < 40; ++c) acc[c] = 0.f;

    for (int k0 = 0; k0 < 128; k0 += 4) {
        float4 v = *(const float4*)&out1[(size_t)n * 128 + k0];
        float xj[4] = {v.x, v.y, v.z, v.w};
#pragma unroll
        for (int j = 0; j < 4; ++j) {
            float xb = xj[j];
#pragma unroll
            for (int c0 = 0; c0 < 40; c0 += 4) {
                float4 w = *(const float4*)&Ws[(k0 + j) * 40 + c0];
                acc[c0 + 0] = fmaf(xb, w.x, acc[c0 + 0]);
                acc[c0 + 1] = fmaf(xb, w.y, acc[c0 + 1]);
                acc[c0 + 2] = fmaf(xb, w.z, acc[c0 + 2]);
                acc[c0 + 3] = fmaf(xb, w.w, acc[c0 + 3]);
            }
        }
    }
    float s2 = 0.f, d2 = 0.f;
#pragma unroll
    for (int c = 0; c < 40; ++c) {
        s2 = fmaf(acc[c], att_s2[c], s2);
        d2 = fmaf(acc[c], att_d2[c], d2);
    }
#pragma unroll
    for (int c0 = 0; c0 < 40; c0 += 4)
        *(float4*)&h2[(size_t)n * 40 + c0] = make_float4(acc[c0], acc[c0 + 1], acc[c0 + 2], acc[c0 + 3]);
    a_src2[n] = s2;
    a_dst2[n] = d2;
}

// ---------------------------------------------------------------------------
// Layer-2 aggregation: one wave per dst node (H=1, C=40). Lanes 0..39 own
// channels. Writes final output (+bias2) directly.
// ---------------------------------------------------------------------------
__global__ __launch_bounds__(256) void k_aggr2(const int* __restrict__ rowptr,
                                               const int* __restrict__ cnt,
                                               const int* __restrict__ col,
                                               const float* __restrict__ a_src,
                                               const float* __restrict__ a_dst,
                                               const float* __restrict__ h2,
                                               const float* __restrict__ bias2,
                                               float* __restrict__ out, int N) {
    int t = threadIdx.x;
    int node = blockIdx.x * 4 + (t >> 6);
    int lane = t & 63;
    if (node >= N) return;
    int beg = rowptr[node];
    int deg = cnt[node];
    float ad = a_dst[node];

    float m = -3.402823466e38f;
    int s = col[beg];
    for (int i = 0; i < deg; ++i) {
        int sn = (i + 1 < deg) ? col[beg + i + 1] : s;
        float v = lrelu(a_src[s] + ad);
        m = fmaxf(m, v);
        s = sn;
    }
    float den = 0.f, acc = 0.f;
    s = col[beg];
    for (int i = 0; i < deg; ++i) {
        int sn = (i + 1 < deg) ? col[beg + i + 1] : s;
        float v = lrelu(a_src[s] + ad);
        float ev = __expf(v - m);
        den += ev;
        if (lane < 40) acc = fmaf(ev, h2[(size_t)s * 40 + lane], acc);
        s = sn;
    }
    if (lane < 40)
        out[(size_t)node * 40 + lane] = acc / (den + 1e-16f) + bias2[lane];
}

// ---------------------------------------------------------------------------
extern "C" void kernel_launch(void* const* d_in, const int* in_sizes, int n_in,
                              void* d_out, int out_size, void* d_ws, size_t ws_size,
                              hipStream_t stream) {
    const float* x   = (const float*)d_in[0];
    const int*   ei  = (const int*)d_in[1];
    const float* W1  = (const float*)d_in[2];
    const float* as1 = (const float*)d_in[3];
    const float* ad1 = (const float*)d_in[4];
    const float* b1  = (const float*)d_in[5];
    const float* W2  = (const float*)d_in[6];
    const float* as2 = (const float*)d_in[7];
    const float* ad2 = (const float*)d_in[8];
    const float* b2  = (const float*)d_in[9];

    int N = in_sizes[0] / 128;
    int E = in_sizes[1] / 2;
    int EN = E + N;
    size_t Np = (size_t)((N + 3) & ~3);

    float* ws = (float*)d_ws;
    float* h1      = ws; ws += Np * 128;
    float* out1    = ws; ws += Np * 128;
    float* a_src1  = ws; ws += Np * 8;
    float* a_dst1  = ws; ws += Np * 8;
    float* h2      = ws; ws += Np * 40;
    float* a_src2v = ws; ws += Np;
    float* a_dst2v = ws; ws += Np;
    int* cnt    = (int*)ws; ws += Np;
    int* cur    = (int*)ws; ws += Np;
    int* rowptr = (int*)ws; ws += Np;
    int* psum   = (int*)ws; ws += 256;
    int* col    = (int*)ws; ws += ((size_t)EN + 3) & ~3;

    int nb = (N + 1023) / 1024;  // scan blocks (<=256)

    k_init<<<256, 256, 0, stream>>>(cnt, cur, N);
    k_hist<<<(EN + 255) / 256, 256, 0, stream>>>(ei, E, N, cnt);
    k_scan_part<<<nb, 256, 0, stream>>>(cnt, N, psum);
    k_scan_mid<<<1, 256, 0, stream>>>(psum, nb);
    k_scan_add<<<nb, 256, 0, stream>>>(cnt, N, psum, rowptr);
    k_scatter<<<(EN + 255) / 256, 256, 0, stream>>>(ei, E, N, rowptr, cur, col);

    k_gemm1<<<(N + 15) / 16, 256, 0, stream>>>(x, W1, as1, ad1, h1, a_src1, a_dst1, N);
    k_aggr1<<<(N + 3) / 4, 256, 0, stream>>>(rowptr, cnt, col, a_src1, a_dst1, h1, b1, out1, N);
    k_gemm2<<<(N + 255) / 256, 256, 0, stream>>>(out1, W2, as2, ad2, h2, a_src2v, a_dst2v, N);
    k_aggr2<<<(N + 3) / 4, 256, 0, stream>>>(rowptr, cnt, col, a_src2v, a_dst2v, h2, b2, (float*)d_out, N);
}

// Round 3
// 451.268 us; speedup vs baseline: 18.2306x; 1.1442x over previous
//
#include <hip/hip_runtime.h>
#include <hip/hip_bf16.h>
#include <math.h>

#define NEG_SLOPE 0.2f

__device__ __forceinline__ float lrelu(float x) { return x > 0.f ? x : NEG_SLOPE * x; }

// ---------------------------------------------------------------------------
// init: zero cnt + cursor (int)
// ---------------------------------------------------------------------------
__global__ __launch_bounds__(256) void k_init(int* __restrict__ cnt, int* __restrict__ cur, int N) {
    int i = blockIdx.x * 256 + threadIdx.x;
    int stride = gridDim.x * 256;
    for (int j = i; j < N; j += stride) { cnt[j] = 0; cur[j] = 0; }
}

// ---------------------------------------------------------------------------
// histogram of dst (incl. self-loops)
// ---------------------------------------------------------------------------
__global__ __launch_bounds__(256) void k_hist(const int* __restrict__ ei, int E, int N,
                                              int* __restrict__ cnt) {
    int e = blockIdx.x * 256 + threadIdx.x;
    if (e >= E + N) return;
    int d = (e < E) ? ei[E + e] : (e - E);
    atomicAdd(&cnt[d], 1);
}

// ---------------------------------------------------------------------------
// 3-stage exclusive scan of cnt[N] -> rowptr[N]; chunk = 1024 per block
// ---------------------------------------------------------------------------
__global__ __launch_bounds__(256) void k_scan_part(const int* __restrict__ cnt, int N,
                                                   int* __restrict__ psum) {
    __shared__ int sh[256];
    int t = threadIdx.x;
    int base = blockIdx.x * 1024 + t * 4;
    int tl = 0;
#pragma unroll
    for (int j = 0; j < 4; ++j) tl += (base + j < N) ? cnt[base + j] : 0;
    sh[t] = tl; __syncthreads();
    for (int off = 128; off > 0; off >>= 1) {
        if (t < off) sh[t] += sh[t + off];
        __syncthreads();
    }
    if (t == 0) psum[blockIdx.x] = sh[0];
}

__global__ __launch_bounds__(256) void k_scan_mid(int* __restrict__ psum, int nb) {
    __shared__ int sh[256];
    int t = threadIdx.x;
    int v = (t < nb) ? psum[t] : 0;
    sh[t] = v; __syncthreads();
    for (int off = 1; off < 256; off <<= 1) {
        int a = (t >= off) ? sh[t - off] : 0;
        __syncthreads();
        sh[t] += a;
        __syncthreads();
    }
    psum[t] = sh[t] - v;  // exclusive
}

__global__ __launch_bounds__(256) void k_scan_add(const int* __restrict__ cnt, int N,
                                                  const int* __restrict__ psum,
                                                  int* __restrict__ rowptr) {
    __shared__ int sh[256];
    int t = threadIdx.x;
    int base = blockIdx.x * 1024 + t * 4;
    int c[4]; int tl = 0;
#pragma unroll
    for (int j = 0; j < 4; ++j) { c[j] = (base + j < N) ? cnt[base + j] : 0; tl += c[j]; }
    sh[t] = tl; __syncthreads();
    for (int off = 1; off < 256; off <<= 1) {
        int a = (t >= off) ? sh[t - off] : 0;
        __syncthreads();
        sh[t] += a;
        __syncthreads();
    }
    int run = psum[blockIdx.x] + (sh[t] - tl);
#pragma unroll
    for (int j = 0; j < 4; ++j) {
        if (base + j < N) { rowptr[base + j] = run; run += c[j]; }
    }
}

// ---------------------------------------------------------------------------
// scatter src into CSR by dst
// ---------------------------------------------------------------------------
__global__ __launch_bounds__(256) void k_scatter(const int* __restrict__ ei, int E, int N,
                                                 const int* __restrict__ rowptr,
                                                 int* __restrict__ cur,
                                                 int* __restrict__ col) {
    int e = blockIdx.x * 256 + threadIdx.x;
    if (e >= E + N) return;
    int s, d;
    if (e < E) { s = ei[e]; d = ei[E + e]; } else { s = d = e - E; }
    int pos = rowptr[d] + atomicAdd(&cur[d], 1);
    col[pos] = s;
}

// ---------------------------------------------------------------------------
// GEMM1: h1 = x @ W1  ([N,128]@[128,128]), fused a_src1/a_dst1 epilogue.
// ---------------------------------------------------------------------------
__global__ __launch_bounds__(256) void k_gemm1(const float* __restrict__ x,
                                               const float* __restrict__ W,
                                               const float* __restrict__ att_s,
                                               const float* __restrict__ att_d,
                                               float* __restrict__ h1,
                                               float* __restrict__ a_src,
                                               float* __restrict__ a_dst, int N) {
    __shared__ float Ws[128 * 128];   // 64 KB
    __shared__ float xs[16 * 132];
    int t = threadIdx.x;
    for (int i = t * 4; i < 128 * 128; i += 256 * 4)
        *(float4*)&Ws[i] = *(const float4*)&W[i];
    int row0 = blockIdx.x * 16;
    for (int idx = t; idx < 16 * 32; idx += 256) {
        int r = idx >> 5, c4 = (idx & 31) * 4;
        int g = row0 + r;
        float4 v = make_float4(0.f, 0.f, 0.f, 0.f);
        if (g < N) v = *(const float4*)&x[(size_t)g * 128 + c4];
        *(float4*)&xs[r * 132 + c4] = v;
    }
    __syncthreads();

    int r = t >> 4;
    int col0 = (t & 15) * 8;
    int g = row0 + r;
    float acc[8] = {0.f, 0.f, 0.f, 0.f, 0.f, 0.f, 0.f, 0.f};
#pragma unroll 8
    for (int k = 0; k < 128; ++k) {
        float xv = xs[r * 132 + k];
        float4 w0 = *(const float4*)&Ws[k * 128 + col0];
        float4 w1 = *(const float4*)&Ws[k * 128 + col0 + 4];
        acc[0] = fmaf(xv, w0.x, acc[0]);
        acc[1] = fmaf(xv, w0.y, acc[1]);
        acc[2] = fmaf(xv, w0.z, acc[2]);
        acc[3] = fmaf(xv, w0.w, acc[3]);
        acc[4] = fmaf(xv, w1.x, acc[4]);
        acc[5] = fmaf(xv, w1.y, acc[5]);
        acc[6] = fmaf(xv, w1.z, acc[6]);
        acc[7] = fmaf(xv, w1.w, acc[7]);
    }
    if (g < N) {
        *(float4*)&h1[(size_t)g * 128 + col0]     = make_float4(acc[0], acc[1], acc[2], acc[3]);
        *(float4*)&h1[(size_t)g * 128 + col0 + 4] = make_float4(acc[4], acc[5], acc[6], acc[7]);
        float ps = 0.f, pd = 0.f;
#pragma unroll
        for (int j = 0; j < 8; ++j) {
            ps = fmaf(acc[j], att_s[col0 + j], ps);
            pd = fmaf(acc[j], att_d[col0 + j], pd);
        }
        ps += __shfl_xor(ps, 1);
        pd += __shfl_xor(pd, 1);
        if ((t & 1) == 0) {
            int head = (t & 15) >> 1;
            a_src[(size_t)g * 8 + head] = ps;
            a_dst[(size_t)g * 8 + head] = pd;
        }
    }
}

// ---------------------------------------------------------------------------
// Layer-1 aggregation: one wave per dst node. Lane l owns channels 2l,2l+1
// (head = l>>3). Single pass (no max shift: alpha bounded ~|2| << 88, exp
// cannot overflow; softmax is shift-invariant). Depth-2 value prefetch.
// Writes finalized out1 = num/denom + bias1.
// ---------------------------------------------------------------------------
__global__ __launch_bounds__(256) void k_aggr1(const int* __restrict__ rowptr,
                                               const int* __restrict__ cnt,
                                               const int* __restrict__ col,
                                               const float* __restrict__ a_src,
                                               const float* __restrict__ a_dst,
                                               const float* __restrict__ h1,
                                               const float* __restrict__ bias1,
                                               float* __restrict__ out1, int N) {
    int t = threadIdx.x;
    int node = blockIdx.x * 4 + (t >> 6);
    int lane = t & 63;
    if (node >= N) return;
    int beg = rowptr[node];
    int deg = cnt[node];
    int last = beg + deg - 1;
    int h = lane >> 3;
    float adh = a_dst[(size_t)node * 8 + h];

    // pipeline prologue: edges 0 and 1 in flight
    int s0 = col[beg];
    float a0 = a_src[(size_t)s0 * 8 + h];
    float2 v0 = *(const float2*)&h1[(size_t)s0 * 128 + 2 * lane];
    int j1 = (beg + 1 <= last) ? beg + 1 : last;
    int s1 = col[j1];
    float a1 = a_src[(size_t)s1 * 8 + h];
    float2 v1 = *(const float2*)&h1[(size_t)s1 * 128 + 2 * lane];

    float den = 0.f, n0 = 0.f, n1 = 0.f;
    for (int i = 0; i < deg; ++i) {
        int j2 = (beg + i + 2 <= last) ? beg + i + 2 : last;
        int s2 = col[j2];
        float a2 = a_src[(size_t)s2 * 8 + h];
        float2 v2 = *(const float2*)&h1[(size_t)s2 * 128 + 2 * lane];
        float ev = __expf(lrelu(a0 + adh));
        den += ev;
        n0 = fmaf(ev, v0.x, n0);
        n1 = fmaf(ev, v0.y, n1);
        a0 = a1; v0 = v1;
        a1 = a2; v1 = v2;
    }
    float inv = 1.f / (den + 1e-16f);
    float2 b = *(const float2*)&bias1[2 * lane];
    float2 o = make_float2(fmaf(n0, inv, b.x), fmaf(n1, inv, b.y));
    *(float2*)&out1[(size_t)node * 128 + 2 * lane] = o;
}

// ---------------------------------------------------------------------------
// GEMM2: h2 = out1 @ W2  ([N,128]@[128,40]); fused a_src2/a_dst2 epilogue.
// ---------------------------------------------------------------------------
__global__ __launch_bounds__(256) void k_gemm2(const float* __restrict__ out1,
                                               const float* __restrict__ W2,
                                               const float* __restrict__ att_s2,
                                               const float* __restrict__ att_d2,
                                               float* __restrict__ h2,
                                               float* __restrict__ a_src2,
                                               float* __restrict__ a_dst2, int N) {
    __shared__ float Ws[128 * 40];
    int t = threadIdx.x;
    for (int i = t * 4; i < 128 * 40; i += 256 * 4)
        *(float4*)&Ws[i] = *(const float4*)&W2[i];
    __syncthreads();
    int n = blockIdx.x * 256 + t;
    if (n >= N) return;

    float acc[40];
#pragma unroll
    for (int c = 0; c < 40; ++c) acc[c] = 0.f;

    for (int k0 = 0; k0 < 128; k0 += 4) {
        float4 v = *(const float4*)&out1[(size_t)n * 128 + k0];
        float xj[4] = {v.x, v.y, v.z, v.w};
#pragma unroll
        for (int j = 0; j < 4; ++j) {
            float xb = xj[j];
#pragma unroll
            for (int c0 = 0; c0 < 40; c0 += 4) {
                float4 w = *(const float4*)&Ws[(k0 + j) * 40 + c0];
                acc[c0 + 0] = fmaf(xb, w.x, acc[c0 + 0]);
                acc[c0 + 1] = fmaf(xb, w.y, acc[c0 + 1]);
                acc[c0 + 2] = fmaf(xb, w.z, acc[c0 + 2]);
                acc[c0 + 3] = fmaf(xb, w.w, acc[c0 + 3]);
            }
        }
    }
    float s2 = 0.f, d2 = 0.f;
#pragma unroll
    for (int c = 0; c < 40; ++c) {
        s2 = fmaf(acc[c], att_s2[c], s2);
        d2 = fmaf(acc[c], att_d2[c], d2);
    }
#pragma unroll
    for (int c0 = 0; c0 < 40; c0 += 4)
        *(float4*)&h2[(size_t)n * 40 + c0] = make_float4(acc[c0], acc[c0 + 1], acc[c0 + 2], acc[c0 + 3]);
    a_src2[n] = s2;
    a_dst2[n] = d2;
}

// ---------------------------------------------------------------------------
// Layer-2 aggregation: one wave per dst node (H=1, C=40). Lanes 0..39 own
// channels (others redundantly load ch 39). Single pass, depth-2 prefetch.
// Writes final output (+bias2) directly.
// ---------------------------------------------------------------------------
__global__ __launch_bounds__(256) void k_aggr2(const int* __restrict__ rowptr,
                                               const int* __restrict__ cnt,
                                               const int* __restrict__ col,
                                               const float* __restrict__ a_src,
                                               const float* __restrict__ a_dst,
                                               const float* __restrict__ h2,
                                               const float* __restrict__ bias2,
                                               float* __restrict__ out, int N) {
    int t = threadIdx.x;
    int node = blockIdx.x * 4 + (t >> 6);
    int lane = t & 63;
    if (node >= N) return;
    int beg = rowptr[node];
    int deg = cnt[node];
    int last = beg + deg - 1;
    int cl = (lane < 40) ? lane : 39;
    float ad = a_dst[node];

    int s0 = col[beg];
    float a0 = a_src[s0];
    float v0 = h2[(size_t)s0 * 40 + cl];
    int j1 = (beg + 1 <= last) ? beg + 1 : last;
    int s1 = col[j1];
    float a1 = a_src[s1];
    float v1 = h2[(size_t)s1 * 40 + cl];

    float den = 0.f, acc = 0.f;
    for (int i = 0; i < deg; ++i) {
        int j2 = (beg + i + 2 <= last) ? beg + i + 2 : last;
        int s2 = col[j2];
        float a2 = a_src[s2];
        float v2 = h2[(size_t)s2 * 40 + cl];
        float ev = __expf(lrelu(a0 + ad));
        den += ev;
        acc = fmaf(ev, v0, acc);
        a0 = a1; v0 = v1;
        a1 = a2; v1 = v2;
    }
    if (lane < 40)
        out[(size_t)node * 40 + lane] = acc / (den + 1e-16f) + bias2[lane];
}

// ---------------------------------------------------------------------------
extern "C" void kernel_launch(void* const* d_in, const int* in_sizes, int n_in,
                              void* d_out, int out_size, void* d_ws, size_t ws_size,
                              hipStream_t stream) {
    const float* x   = (const float*)d_in[0];
    const int*   ei  = (const int*)d_in[1];
    const float* W1  = (const float*)d_in[2];
    const float* as1 = (const float*)d_in[3];
    const float* ad1 = (const float*)d_in[4];
    const float* b1  = (const float*)d_in[5];
    const float* W2  = (const float*)d_in[6];
    const float* as2 = (const float*)d_in[7];
    const float* ad2 = (const float*)d_in[8];
    const float* b2  = (const float*)d_in[9];

    int N = in_sizes[0] / 128;
    int E = in_sizes[1] / 2;
    int EN = E + N;
    size_t Np = (size_t)((N + 3) & ~3);

    float* ws = (float*)d_ws;
    float* h1      = ws; ws += Np * 128;
    float* out1    = ws; ws += Np * 128;
    float* a_src1  = ws; ws += Np * 8;
    float* a_dst1  = ws; ws += Np * 8;
    float* h2      = ws; ws += Np * 40;
    float* a_src2v = ws; ws += Np;
    float* a_dst2v = ws; ws += Np;
    int* cnt    = (int*)ws; ws += Np;
    int* cur    = (int*)ws; ws += Np;
    int* rowptr = (int*)ws; ws += Np;
    int* psum   = (int*)ws; ws += 256;
    int* col    = (int*)ws; ws += ((size_t)EN + 3) & ~3;

    int nb = (N + 1023) / 1024;  // scan blocks (<=256)

    k_init<<<256, 256, 0, stream>>>(cnt, cur, N);
    k_hist<<<(EN + 255) / 256, 256, 0, stream>>>(ei, E, N, cnt);
    k_scan_part<<<nb, 256, 0, stream>>>(cnt, N, psum);
    k_scan_mid<<<1, 256, 0, stream>>>(psum, nb);
    k_scan_add<<<nb, 256, 0, stream>>>(cnt, N, psum, rowptr);
    k_scatter<<<(EN + 255) / 256, 256, 0, stream>>>(ei, E, N, rowptr, cur, col);

    k_gemm1<<<(N + 15) / 16, 256, 0, stream>>>(x, W1, as1, ad1, h1, a_src1, a_dst1, N);
    k_aggr1<<<(N + 3) / 4, 256, 0, stream>>>(rowptr, cnt, col, a_src1, a_dst1, h1, b1, out1, N);
    k_gemm2<<<(N + 255) / 256, 256, 0, stream>>>(out1, W2, as2, ad2, h2, a_src2v, a_dst2v, N);
    k_aggr2<<<(N + 3) / 4, 256, 0, stream>>>(rowptr, cnt, col, a_src2v, a_dst2v, h2, b2, (float*)d_out, N);
}

// Round 4
// 442.482 us; speedup vs baseline: 18.5926x; 1.0199x over previous
//
#include <hip/hip_runtime.h>
#include <hip/hip_bf16.h>
#include <math.h>

#define NEG_SLOPE 0.2f

__device__ __forceinline__ float lrelu(float x) { return x > 0.f ? x : NEG_SLOPE * x; }

// pack two fp32 -> one uint holding 2 bf16 (RNE)
__device__ __forceinline__ unsigned int pack_bf2(float a, float b) {
    unsigned int ua = __float_as_uint(a);
    ua = (ua + 0x7fffu + ((ua >> 16) & 1u)) >> 16;
    unsigned int ub = __float_as_uint(b);
    ub = (ub + 0x7fffu + ((ub >> 16) & 1u)) & 0xffff0000u;
    return ua | ub;
}
__device__ __forceinline__ unsigned short pack_bf1(float a) {
    unsigned int ua = __float_as_uint(a);
    return (unsigned short)((ua + 0x7fffu + ((ua >> 16) & 1u)) >> 16);
}
__device__ __forceinline__ float bf_lo(unsigned int u) { return __uint_as_float(u << 16); }
__device__ __forceinline__ float bf_hi(unsigned int u) { return __uint_as_float(u & 0xffff0000u); }

// ---------------------------------------------------------------------------
// init: zero cnt + cursor (int)
// ---------------------------------------------------------------------------
__global__ __launch_bounds__(256) void k_init(int* __restrict__ cnt, int* __restrict__ cur, int N) {
    int i = blockIdx.x * 256 + threadIdx.x;
    int stride = gridDim.x * 256;
    for (int j = i; j < N; j += stride) { cnt[j] = 0; cur[j] = 0; }
}

// ---------------------------------------------------------------------------
// histogram of dst (incl. self-loops)
// ---------------------------------------------------------------------------
__global__ __launch_bounds__(256) void k_hist(const int* __restrict__ ei, int E, int N,
                                              int* __restrict__ cnt) {
    int e = blockIdx.x * 256 + threadIdx.x;
    if (e >= E + N) return;
    int d = (e < E) ? ei[E + e] : (e - E);
    atomicAdd(&cnt[d], 1);
}

// ---------------------------------------------------------------------------
// 3-stage exclusive scan of cnt[N] -> rowptr[N]; chunk = 1024 per block
// ---------------------------------------------------------------------------
__global__ __launch_bounds__(256) void k_scan_part(const int* __restrict__ cnt, int N,
                                                   int* __restrict__ psum) {
    __shared__ int sh[256];
    int t = threadIdx.x;
    int base = blockIdx.x * 1024 + t * 4;
    int tl = 0;
#pragma unroll
    for (int j = 0; j < 4; ++j) tl += (base + j < N) ? cnt[base + j] : 0;
    sh[t] = tl; __syncthreads();
    for (int off = 128; off > 0; off >>= 1) {
        if (t < off) sh[t] += sh[t + off];
        __syncthreads();
    }
    if (t == 0) psum[blockIdx.x] = sh[0];
}

__global__ __launch_bounds__(256) void k_scan_mid(int* __restrict__ psum, int nb) {
    __shared__ int sh[256];
    int t = threadIdx.x;
    int v = (t < nb) ? psum[t] : 0;
    sh[t] = v; __syncthreads();
    for (int off = 1; off < 256; off <<= 1) {
        int a = (t >= off) ? sh[t - off] : 0;
        __syncthreads();
        sh[t] += a;
        __syncthreads();
    }
    psum[t] = sh[t] - v;  // exclusive
}

__global__ __launch_bounds__(256) void k_scan_add(const int* __restrict__ cnt, int N,
                                                  const int* __restrict__ psum,
                                                  int* __restrict__ rowptr) {
    __shared__ int sh[256];
    int t = threadIdx.x;
    int base = blockIdx.x * 1024 + t * 4;
    int c[4]; int tl = 0;
#pragma unroll
    for (int j = 0; j < 4; ++j) { c[j] = (base + j < N) ? cnt[base + j] : 0; tl += c[j]; }
    sh[t] = tl; __syncthreads();
    for (int off = 1; off < 256; off <<= 1) {
        int a = (t >= off) ? sh[t - off] : 0;
        __syncthreads();
        sh[t] += a;
        __syncthreads();
    }
    int run = psum[blockIdx.x] + (sh[t] - tl);
#pragma unroll
    for (int j = 0; j < 4; ++j) {
        if (base + j < N) { rowptr[base + j] = run; run += c[j]; }
    }
}

// ---------------------------------------------------------------------------
// scatter src into CSR by dst
// ---------------------------------------------------------------------------
__global__ __launch_bounds__(256) void k_scatter(const int* __restrict__ ei, int E, int N,
                                                 const int* __restrict__ rowptr,
                                                 int* __restrict__ cur,
                                                 int* __restrict__ col) {
    int e = blockIdx.x * 256 + threadIdx.x;
    if (e >= E + N) return;
    int s, d;
    if (e < E) { s = ei[e]; d = ei[E + e]; } else { s = d = e - E; }
    int pos = rowptr[d] + atomicAdd(&cur[d], 1);
    col[pos] = s;
}

// ---------------------------------------------------------------------------
// GEMM1: h1 = x @ W1 ([N,128]@[128,128]); emits h1 as packed bf16 rows
// (256 B/row) + fused fp32 a_src1/a_dst1.
// ---------------------------------------------------------------------------
__global__ __launch_bounds__(256) void k_gemm1(const float* __restrict__ x,
                                               const float* __restrict__ W,
                                               const float* __restrict__ att_s,
                                               const float* __restrict__ att_d,
                                               unsigned int* __restrict__ h1b,  // [N][64] uints
                                               float* __restrict__ a_src,
                                               float* __restrict__ a_dst, int N) {
    __shared__ float Ws[128 * 128];   // 64 KB
    __shared__ float xs[16 * 132];
    int t = threadIdx.x;
    for (int i = t * 4; i < 128 * 128; i += 256 * 4)
        *(float4*)&Ws[i] = *(const float4*)&W[i];
    int row0 = blockIdx.x * 16;
    for (int idx = t; idx < 16 * 32; idx += 256) {
        int r = idx >> 5, c4 = (idx & 31) * 4;
        int g = row0 + r;
        float4 v = make_float4(0.f, 0.f, 0.f, 0.f);
        if (g < N) v = *(const float4*)&x[(size_t)g * 128 + c4];
        *(float4*)&xs[r * 132 + c4] = v;
    }
    __syncthreads();

    int r = t >> 4;
    int col0 = (t & 15) * 8;
    int g = row0 + r;
    float acc[8] = {0.f, 0.f, 0.f, 0.f, 0.f, 0.f, 0.f, 0.f};
#pragma unroll 8
    for (int k = 0; k < 128; ++k) {
        float xv = xs[r * 132 + k];
        float4 w0 = *(const float4*)&Ws[k * 128 + col0];
        float4 w1 = *(const float4*)&Ws[k * 128 + col0 + 4];
        acc[0] = fmaf(xv, w0.x, acc[0]);
        acc[1] = fmaf(xv, w0.y, acc[1]);
        acc[2] = fmaf(xv, w0.z, acc[2]);
        acc[3] = fmaf(xv, w0.w, acc[3]);
        acc[4] = fmaf(xv, w1.x, acc[4]);
        acc[5] = fmaf(xv, w1.y, acc[5]);
        acc[6] = fmaf(xv, w1.z, acc[6]);
        acc[7] = fmaf(xv, w1.w, acc[7]);
    }
    if (g < N) {
        uint4 p = make_uint4(pack_bf2(acc[0], acc[1]), pack_bf2(acc[2], acc[3]),
                             pack_bf2(acc[4], acc[5]), pack_bf2(acc[6], acc[7]));
        *(uint4*)&h1b[(size_t)g * 64 + col0 / 2] = p;
        float ps = 0.f, pd = 0.f;
#pragma unroll
        for (int j = 0; j < 8; ++j) {
            ps = fmaf(acc[j], att_s[col0 + j], ps);
            pd = fmaf(acc[j], att_d[col0 + j], pd);
        }
        ps += __shfl_xor(ps, 1);
        pd += __shfl_xor(pd, 1);
        if ((t & 1) == 0) {
            int head = (t & 15) >> 1;
            a_src[(size_t)g * 8 + head] = ps;
            a_dst[(size_t)g * 8 + head] = pd;
        }
    }
}

// ---------------------------------------------------------------------------
// Layer-1 aggregation: one wave per dst node. Lane l owns channels 2l,2l+1
// (one bf16x2 uint per lane, head = l>>3). Single pass, depth-3 prefetch.
// Writes finalized fp32 out1 = num/denom + bias1.
// ---------------------------------------------------------------------------
__global__ __launch_bounds__(256) void k_aggr1(const int* __restrict__ rowptr,
                                               const int* __restrict__ cnt,
                                               const int* __restrict__ col,
                                               const float* __restrict__ a_src,
                                               const float* __restrict__ a_dst,
                                               const unsigned int* __restrict__ h1b,
                                               const float* __restrict__ bias1,
                                               float* __restrict__ out1, int N) {
    int t = threadIdx.x;
    int node = blockIdx.x * 4 + (t >> 6);
    int lane = t & 63;
    if (node >= N) return;
    int beg = rowptr[node];
    int deg = cnt[node];
    int last = beg + deg - 1;
    int h = lane >> 3;
    float adh = a_dst[(size_t)node * 8 + h];

    // depth-3 pipeline prologue
    int s0 = col[beg];
    float a0 = a_src[(size_t)s0 * 8 + h];
    unsigned int u0 = h1b[(size_t)s0 * 64 + lane];
    int j1 = (beg + 1 <= last) ? beg + 1 : last;
    int s1 = col[j1];
    float a1 = a_src[(size_t)s1 * 8 + h];
    unsigned int u1 = h1b[(size_t)s1 * 64 + lane];
    int j2 = (beg + 2 <= last) ? beg + 2 : last;
    int s2 = col[j2];
    float a2 = a_src[(size_t)s2 * 8 + h];
    unsigned int u2 = h1b[(size_t)s2 * 64 + lane];

    float den = 0.f, n0 = 0.f, n1 = 0.f;
    for (int i = 0; i < deg; ++i) {
        int j3 = (beg + i + 3 <= last) ? beg + i + 3 : last;
        int s3 = col[j3];
        float a3 = a_src[(size_t)s3 * 8 + h];
        unsigned int u3 = h1b[(size_t)s3 * 64 + lane];
        float ev = __expf(lrelu(a0 + adh));
        den += ev;
        n0 = fmaf(ev, bf_lo(u0), n0);
        n1 = fmaf(ev, bf_hi(u0), n1);
        a0 = a1; u0 = u1;
        a1 = a2; u1 = u2;
        a2 = a3; u2 = u3;
    }
    float inv = 1.f / (den + 1e-16f);
    float2 b = *(const float2*)&bias1[2 * lane];
    float2 o = make_float2(fmaf(n0, inv, b.x), fmaf(n1, inv, b.y));
    *(float2*)&out1[(size_t)node * 128 + 2 * lane] = o;
}

// ---------------------------------------------------------------------------
// GEMM2: h2 = out1 @ W2 ([N,128]@[128,40]); emits h2 as packed bf16 rows
// (80 B/row) + fused fp32 a_src2/a_dst2.
// ---------------------------------------------------------------------------
__global__ __launch_bounds__(256) void k_gemm2(const float* __restrict__ out1,
                                               const float* __restrict__ W2,
                                               const float* __restrict__ att_s2,
                                               const float* __restrict__ att_d2,
                                               unsigned int* __restrict__ h2b,  // [N][20] uints
                                               float* __restrict__ a_src2,
                                               float* __restrict__ a_dst2, int N) {
    __shared__ float Ws[128 * 40];
    int t = threadIdx.x;
    for (int i = t * 4; i < 128 * 40; i += 256 * 4)
        *(float4*)&Ws[i] = *(const float4*)&W2[i];
    __syncthreads();
    int n = blockIdx.x * 256 + t;
    if (n >= N) return;

    float acc[40];
#pragma unroll
    for (int c = 0; c < 40; ++c) acc[c] = 0.f;

    for (int k0 = 0; k0 < 128; k0 += 4) {
        float4 v = *(const float4*)&out1[(size_t)n * 128 + k0];
        float xj[4] = {v.x, v.y, v.z, v.w};
#pragma unroll
        for (int j = 0; j < 4; ++j) {
            float xb = xj[j];
#pragma unroll
            for (int c0 = 0; c0 < 40; c0 += 4) {
                float4 w = *(const float4*)&Ws[(k0 + j) * 40 + c0];
                acc[c0 + 0] = fmaf(xb, w.x, acc[c0 + 0]);
                acc[c0 + 1] = fmaf(xb, w.y, acc[c0 + 1]);
                acc[c0 + 2] = fmaf(xb, w.z, acc[c0 + 2]);
                acc[c0 + 3] = fmaf(xb, w.w, acc[c0 + 3]);
            }
        }
    }
    float s2 = 0.f, d2 = 0.f;
#pragma unroll
    for (int c = 0; c < 40; ++c) {
        s2 = fmaf(acc[c], att_s2[c], s2);
        d2 = fmaf(acc[c], att_d2[c], d2);
    }
    unsigned int p[20];
#pragma unroll
    for (int j = 0; j < 20; ++j) p[j] = pack_bf2(acc[2 * j], acc[2 * j + 1]);
#pragma unroll
    for (int j = 0; j < 5; ++j)
        *(uint4*)&h2b[(size_t)n * 20 + 4 * j] = make_uint4(p[4 * j], p[4 * j + 1], p[4 * j + 2], p[4 * j + 3]);
    a_src2[n] = s2;
    a_dst2[n] = d2;
}

// ---------------------------------------------------------------------------
// Layer-2 aggregation: one wave per dst node (H=1, C=40). Lanes 0..39 own
// channels (bf16 scalar loads). Single pass, depth-3 prefetch. Writes final
// output (+bias2) directly.
// ---------------------------------------------------------------------------
__global__ __launch_bounds__(256) void k_aggr2(const int* __restrict__ rowptr,
                                               const int* __restrict__ cnt,
                                               const int* __restrict__ col,
                                               const float* __restrict__ a_src,
                                               const float* __restrict__ a_dst,
                                               const unsigned short* __restrict__ h2b,
                                               const float* __restrict__ bias2,
                                               float* __restrict__ out, int N) {
    int t = threadIdx.x;
    int node = blockIdx.x * 4 + (t >> 6);
    int lane = t & 63;
    if (node >= N) return;
    int beg = rowptr[node];
    int deg = cnt[node];
    int last = beg + deg - 1;
    int cl = (lane < 40) ? lane : 39;
    float ad = a_dst[node];

    int s0 = col[beg];
    float a0 = a_src[s0];
    unsigned int u0 = h2b[(size_t)s0 * 40 + cl];
    int j1 = (beg + 1 <= last) ? beg + 1 : last;
    int s1 = col[j1];
    float a1 = a_src[s1];
    unsigned int u1 = h2b[(size_t)s1 * 40 + cl];
    int j2 = (beg + 2 <= last) ? beg + 2 : last;
    int s2 = col[j2];
    float a2 = a_src[s2];
    unsigned int u2 = h2b[(size_t)s2 * 40 + cl];

    float den = 0.f, acc = 0.f;
    for (int i = 0; i < deg; ++i) {
        int j3 = (beg + i + 3 <= last) ? beg + i + 3 : last;
        int s3 = col[j3];
        float a3 = a_src[s3];
        unsigned int u3 = h2b[(size_t)s3 * 40 + cl];
        float ev = __expf(lrelu(a0 + ad));
        den += ev;
        acc = fmaf(ev, __uint_as_float(u0 << 16), acc);
        a0 = a1; u0 = u1;
        a1 = a2; u1 = u2;
        a2 = a3; u2 = u3;
    }
    if (lane < 40)
        out[(size_t)node * 40 + lane] = acc / (den + 1e-16f) + bias2[lane];
}

// ---------------------------------------------------------------------------
extern "C" void kernel_launch(void* const* d_in, const int* in_sizes, int n_in,
                              void* d_out, int out_size, void* d_ws, size_t ws_size,
                              hipStream_t stream) {
    const float* x   = (const float*)d_in[0];
    const int*   ei  = (const int*)d_in[1];
    const float* W1  = (const float*)d_in[2];
    const float* as1 = (const float*)d_in[3];
    const float* ad1 = (const float*)d_in[4];
    const float* b1  = (const float*)d_in[5];
    const float* W2  = (const float*)d_in[6];
    const float* as2 = (const float*)d_in[7];
    const float* ad2 = (const float*)d_in[8];
    const float* b2  = (const float*)d_in[9];

    int N = in_sizes[0] / 128;
    int E = in_sizes[1] / 2;
    int EN = E + N;
    size_t Np = (size_t)((N + 3) & ~3);

    float* ws = (float*)d_ws;
    float* out1    = ws; ws += Np * 128;
    unsigned int* h1b = (unsigned int*)ws; ws += Np * 64;   // bf16x2 per uint
    unsigned int* h2b = (unsigned int*)ws; ws += Np * 20;
    float* a_src1  = ws; ws += Np * 8;
    float* a_dst1  = ws; ws += Np * 8;
    float* a_src2v = ws; ws += Np;
    float* a_dst2v = ws; ws += Np;
    int* cnt    = (int*)ws; ws += Np;
    int* cur    = (int*)ws; ws += Np;
    int* rowptr = (int*)ws; ws += Np;
    int* psum   = (int*)ws; ws += 256;
    int* col    = (int*)ws; ws += ((size_t)EN + 3) & ~3;

    int nb = (N + 1023) / 1024;  // scan blocks (<=256)

    k_init<<<256, 256, 0, stream>>>(cnt, cur, N);
    k_hist<<<(EN + 255) / 256, 256, 0, stream>>>(ei, E, N, cnt);
    k_scan_part<<<nb, 256, 0, stream>>>(cnt, N, psum);
    k_scan_mid<<<1, 256, 0, stream>>>(psum, nb);
    k_scan_add<<<nb, 256, 0, stream>>>(cnt, N, psum, rowptr);
    k_scatter<<<(EN + 255) / 256, 256, 0, stream>>>(ei, E, N, rowptr, cur, col);

    k_gemm1<<<(N + 15) / 16, 256, 0, stream>>>(x, W1, as1, ad1, h1b, a_src1, a_dst1, N);
    k_aggr1<<<(N + 3) / 4, 256, 0, stream>>>(rowptr, cnt, col, a_src1, a_dst1, h1b, b1, out1, N);
    k_gemm2<<<(N + 255) / 256, 256, 0, stream>>>(out1, W2, as2, ad2, h2b, a_src2v, a_dst2v, N);
    k_aggr2<<<(N + 3) / 4, 256, 0, stream>>>(rowptr, cnt, col, a_src2v, a_dst2v,
                                             (const unsigned short*)h2b, b2, (float*)d_out, N);
}

// Round 5
// 386.675 us; speedup vs baseline: 21.2760x; 1.1443x over previous
//
#include <hip/hip_runtime.h>
#include <hip/hip_bf16.h>
#include <math.h>

#define NEG_SLOPE 0.2f

__device__ __forceinline__ float lrelu(float x) { return x > 0.f ? x : NEG_SLOPE * x; }

// pack two fp32 -> one uint holding 2 bf16 (RNE)
__device__ __forceinline__ unsigned int pack_bf2(float a, float b) {
    unsigned int ua = __float_as_uint(a);
    ua = (ua + 0x7fffu + ((ua >> 16) & 1u)) >> 16;
    unsigned int ub = __float_as_uint(b);
    ub = (ub + 0x7fffu + ((ub >> 16) & 1u)) & 0xffff0000u;
    return ua | ub;
}
__device__ __forceinline__ float bf_lo(unsigned int u) { return __uint_as_float(u << 16); }
__device__ __forceinline__ float bf_hi(unsigned int u) { return __uint_as_float(u & 0xffff0000u); }

// ---------------------------------------------------------------------------
// init: zero cnt + cursor (int)
// ---------------------------------------------------------------------------
__global__ __launch_bounds__(256) void k_init(int* __restrict__ cnt, int* __restrict__ cur, int N) {
    int i = blockIdx.x * 256 + threadIdx.x;
    int stride = gridDim.x * 256;
    for (int j = i; j < N; j += stride) { cnt[j] = 0; cur[j] = 0; }
}

// ---------------------------------------------------------------------------
// histogram of dst (incl. self-loops)
// ---------------------------------------------------------------------------
__global__ __launch_bounds__(256) void k_hist(const int* __restrict__ ei, int E, int N,
                                              int* __restrict__ cnt) {
    int e = blockIdx.x * 256 + threadIdx.x;
    if (e >= E + N) return;
    int d = (e < E) ? ei[E + e] : (e - E);
    atomicAdd(&cnt[d], 1);
}

// ---------------------------------------------------------------------------
// 3-stage exclusive scan of cnt[N] -> rowptr[N]; chunk = 1024 per block
// ---------------------------------------------------------------------------
__global__ __launch_bounds__(256) void k_scan_part(const int* __restrict__ cnt, int N,
                                                   int* __restrict__ psum) {
    __shared__ int sh[256];
    int t = threadIdx.x;
    int base = blockIdx.x * 1024 + t * 4;
    int tl = 0;
#pragma unroll
    for (int j = 0; j < 4; ++j) tl += (base + j < N) ? cnt[base + j] : 0;
    sh[t] = tl; __syncthreads();
    for (int off = 128; off > 0; off >>= 1) {
        if (t < off) sh[t] += sh[t + off];
        __syncthreads();
    }
    if (t == 0) psum[blockIdx.x] = sh[0];
}

__global__ __launch_bounds__(256) void k_scan_mid(int* __restrict__ psum, int nb) {
    __shared__ int sh[256];
    int t = threadIdx.x;
    int v = (t < nb) ? psum[t] : 0;
    sh[t] = v; __syncthreads();
    for (int off = 1; off < 256; off <<= 1) {
        int a = (t >= off) ? sh[t - off] : 0;
        __syncthreads();
        sh[t] += a;
        __syncthreads();
    }
    psum[t] = sh[t] - v;  // exclusive
}

__global__ __launch_bounds__(256) void k_scan_add(const int* __restrict__ cnt, int N,
                                                  const int* __restrict__ psum,
                                                  int* __restrict__ rowptr) {
    __shared__ int sh[256];
    int t = threadIdx.x;
    int base = blockIdx.x * 1024 + t * 4;
    int c[4]; int tl = 0;
#pragma unroll
    for (int j = 0; j < 4; ++j) { c[j] = (base + j < N) ? cnt[base + j] : 0; tl += c[j]; }
    sh[t] = tl; __syncthreads();
    for (int off = 1; off < 256; off <<= 1) {
        int a = (t >= off) ? sh[t - off] : 0;
        __syncthreads();
        sh[t] += a;
        __syncthreads();
    }
    int run = psum[blockIdx.x] + (sh[t] - tl);
#pragma unroll
    for (int j = 0; j < 4; ++j) {
        if (base + j < N) { rowptr[base + j] = run; run += c[j]; }
    }
}

// ---------------------------------------------------------------------------
// scatter src into CSR by dst
// ---------------------------------------------------------------------------
__global__ __launch_bounds__(256) void k_scatter(const int* __restrict__ ei, int E, int N,
                                                 const int* __restrict__ rowptr,
                                                 int* __restrict__ cur,
                                                 int* __restrict__ col) {
    int e = blockIdx.x * 256 + threadIdx.x;
    if (e >= E + N) return;
    int s, d;
    if (e < E) { s = ei[e]; d = ei[E + e]; } else { s = d = e - E; }
    int pos = rowptr[d] + atomicAdd(&cur[d], 1);
    col[pos] = s;
}

// ---------------------------------------------------------------------------
// GEMM1: h1 = x @ W1 ([N,128]@[128,128]); emits h1 as packed bf16 rows
// (256 B/row) + fused fp32 a_src1/a_dst1.
// ---------------------------------------------------------------------------
__global__ __launch_bounds__(256) void k_gemm1(const float* __restrict__ x,
                                               const float* __restrict__ W,
                                               const float* __restrict__ att_s,
                                               const float* __restrict__ att_d,
                                               unsigned int* __restrict__ h1b,  // [N][64] uints
                                               float* __restrict__ a_src,
                                               float* __restrict__ a_dst, int N) {
    __shared__ float Ws[128 * 128];   // 64 KB
    __shared__ float xs[16 * 132];
    int t = threadIdx.x;
    for (int i = t * 4; i < 128 * 128; i += 256 * 4)
        *(float4*)&Ws[i] = *(const float4*)&W[i];
    int row0 = blockIdx.x * 16;
    for (int idx = t; idx < 16 * 32; idx += 256) {
        int r = idx >> 5, c4 = (idx & 31) * 4;
        int g = row0 + r;
        float4 v = make_float4(0.f, 0.f, 0.f, 0.f);
        if (g < N) v = *(const float4*)&x[(size_t)g * 128 + c4];
        *(float4*)&xs[r * 132 + c4] = v;
    }
    __syncthreads();

    int r = t >> 4;
    int col0 = (t & 15) * 8;
    int g = row0 + r;
    float acc[8] = {0.f, 0.f, 0.f, 0.f, 0.f, 0.f, 0.f, 0.f};
#pragma unroll 8
    for (int k = 0; k < 128; ++k) {
        float xv = xs[r * 132 + k];
        float4 w0 = *(const float4*)&Ws[k * 128 + col0];
        float4 w1 = *(const float4*)&Ws[k * 128 + col0 + 4];
        acc[0] = fmaf(xv, w0.x, acc[0]);
        acc[1] = fmaf(xv, w0.y, acc[1]);
        acc[2] = fmaf(xv, w0.z, acc[2]);
        acc[3] = fmaf(xv, w0.w, acc[3]);
        acc[4] = fmaf(xv, w1.x, acc[4]);
        acc[5] = fmaf(xv, w1.y, acc[5]);
        acc[6] = fmaf(xv, w1.z, acc[6]);
        acc[7] = fmaf(xv, w1.w, acc[7]);
    }
    if (g < N) {
        uint4 p = make_uint4(pack_bf2(acc[0], acc[1]), pack_bf2(acc[2], acc[3]),
                             pack_bf2(acc[4], acc[5]), pack_bf2(acc[6], acc[7]));
        *(uint4*)&h1b[(size_t)g * 64 + col0 / 2] = p;
        float ps = 0.f, pd = 0.f;
#pragma unroll
        for (int j = 0; j < 8; ++j) {
            ps = fmaf(acc[j], att_s[col0 + j], ps);
            pd = fmaf(acc[j], att_d[col0 + j], pd);
        }
        ps += __shfl_xor(ps, 1);
        pd += __shfl_xor(pd, 1);
        if ((t & 1) == 0) {
            int head = (t & 15) >> 1;
            a_src[(size_t)g * 8 + head] = ps;
            a_dst[(size_t)g * 8 + head] = pd;
        }
    }
}

// ---------------------------------------------------------------------------
// Layer-1 aggregation: one wave per dst node. Lane l owns channels 2l,2l+1
// (one bf16x2 uint per lane, head = l>>3). Scalar-index scheme: col entries
// preloaded coalesced (one per lane), current src obtained via readlane ->
// SGPR, so gather bases are scalar (saddr-form loads, minimal VALU).
// Depth-2 value pipeline. Writes finalized fp32 out1 = num/denom + bias1.
// ---------------------------------------------------------------------------
__global__ __launch_bounds__(256) void k_aggr1(const int* __restrict__ rowptr,
                                               const int* __restrict__ cnt,
                                               const int* __restrict__ col,
                                               const float* __restrict__ a_src,
                                               const float* __restrict__ a_dst,
                                               const unsigned int* __restrict__ h1b,
                                               const float* __restrict__ bias1,
                                               float* __restrict__ out1, int N) {
    int t = threadIdx.x;
    int node = blockIdx.x * 4 + (t >> 6);
    int lane = t & 63;
    if (node >= N) return;
    int beg = rowptr[node];
    int deg = cnt[node];
    int h = lane >> 3;
    float adh = a_dst[node * 8 + h];

    float den = 0.f, n0 = 0.f, n1 = 0.f;
    int c = 0;
    while (c < deg) {
        int cc = deg - c; cc = (cc < 64) ? cc : 64;
        int colreg = col[beg + c + ((lane < cc) ? lane : (cc - 1))];
        int sA = __builtin_amdgcn_readlane(colreg, 0);
        int iB = (cc > 1) ? 1 : 0;
        int sB = __builtin_amdgcn_readlane(colreg, iB);
        float aA = a_src[sA * 8 + h];
        unsigned int uA = h1b[(sA << 6) + lane];
        float aB = a_src[sB * 8 + h];
        unsigned int uB = h1b[(sB << 6) + lane];
        for (int i = 0; i < cc; ++i) {
            int iC = i + 2; iC = (iC < cc) ? iC : (cc - 1);
            int sC = __builtin_amdgcn_readlane(colreg, iC);
            float aC = a_src[sC * 8 + h];
            unsigned int uC = h1b[(sC << 6) + lane];
            float ev = __expf(lrelu(aA + adh));
            den += ev;
            n0 = fmaf(ev, bf_lo(uA), n0);
            n1 = fmaf(ev, bf_hi(uA), n1);
            aA = aB; uA = uB;
            aB = aC; uB = uC;
        }
        c += cc;
    }
    float inv = 1.f / (den + 1e-16f);
    float2 b = *(const float2*)&bias1[2 * lane];
    float2 o = make_float2(fmaf(n0, inv, b.x), fmaf(n1, inv, b.y));
    *(float2*)&out1[(size_t)node * 128 + 2 * lane] = o;
}

// ---------------------------------------------------------------------------
// GEMM2: h2 = out1 @ W2 ([N,128]@[128,40]); emits h2 as packed bf16 rows
// (80 B/row) + fused fp32 a_src2/a_dst2.
// ---------------------------------------------------------------------------
__global__ __launch_bounds__(256) void k_gemm2(const float* __restrict__ out1,
                                               const float* __restrict__ W2,
                                               const float* __restrict__ att_s2,
                                               const float* __restrict__ att_d2,
                                               unsigned int* __restrict__ h2b,  // [N][20] uints
                                               float* __restrict__ a_src2,
                                               float* __restrict__ a_dst2, int N) {
    __shared__ float Ws[128 * 40];
    int t = threadIdx.x;
    for (int i = t * 4; i < 128 * 40; i += 256 * 4)
        *(float4*)&Ws[i] = *(const float4*)&W2[i];
    __syncthreads();
    int n = blockIdx.x * 256 + t;
    if (n >= N) return;

    float acc[40];
#pragma unroll
    for (int c = 0; c < 40; ++c) acc[c] = 0.f;

    for (int k0 = 0; k0 < 128; k0 += 4) {
        float4 v = *(const float4*)&out1[(size_t)n * 128 + k0];
        float xj[4] = {v.x, v.y, v.z, v.w};
#pragma unroll
        for (int j = 0; j < 4; ++j) {
            float xb = xj[j];
#pragma unroll
            for (int c0 = 0; c0 < 40; c0 += 4) {
                float4 w = *(const float4*)&Ws[(k0 + j) * 40 + c0];
                acc[c0 + 0] = fmaf(xb, w.x, acc[c0 + 0]);
                acc[c0 + 1] = fmaf(xb, w.y, acc[c0 + 1]);
                acc[c0 + 2] = fmaf(xb, w.z, acc[c0 + 2]);
                acc[c0 + 3] = fmaf(xb, w.w, acc[c0 + 3]);
            }
        }
    }
    float s2 = 0.f, d2 = 0.f;
#pragma unroll
    for (int c = 0; c < 40; ++c) {
        s2 = fmaf(acc[c], att_s2[c], s2);
        d2 = fmaf(acc[c], att_d2[c], d2);
    }
    unsigned int p[20];
#pragma unroll
    for (int j = 0; j < 20; ++j) p[j] = pack_bf2(acc[2 * j], acc[2 * j + 1]);
#pragma unroll
    for (int j = 0; j < 5; ++j)
        *(uint4*)&h2b[(size_t)n * 20 + 4 * j] = make_uint4(p[4 * j], p[4 * j + 1], p[4 * j + 2], p[4 * j + 3]);
    a_src2[n] = s2;
    a_dst2[n] = d2;
}

// ---------------------------------------------------------------------------
// Layer-2 aggregation: one wave per dst node (H=1, C=40). Scalar-index
// scheme: src via readlane -> a_src[s] is a scalar load; h2b gather is
// saddr-form. Depth-2 pipeline. Writes final output (+bias2) directly.
// ---------------------------------------------------------------------------
__global__ __launch_bounds__(256) void k_aggr2(const int* __restrict__ rowptr,
                                               const int* __restrict__ cnt,
                                               const int* __restrict__ col,
                                               const float* __restrict__ a_src,
                                               const float* __restrict__ a_dst,
                                               const unsigned short* __restrict__ h2b,
                                               const float* __restrict__ bias2,
                                               float* __restrict__ out, int N) {
    int t = threadIdx.x;
    int node = blockIdx.x * 4 + (t >> 6);
    int lane = t & 63;
    if (node >= N) return;
    int beg = rowptr[node];
    int deg = cnt[node];
    int cl = (lane < 40) ? lane : 39;
    float ad = a_dst[node];

    float den = 0.f, acc = 0.f;
    int c = 0;
    while (c < deg) {
        int cc = deg - c; cc = (cc < 64) ? cc : 64;
        int colreg = col[beg + c + ((lane < cc) ? lane : (cc - 1))];
        int sA = __builtin_amdgcn_readlane(colreg, 0);
        int iB = (cc > 1) ? 1 : 0;
        int sB = __builtin_amdgcn_readlane(colreg, iB);
        float aA = a_src[sA];
        unsigned int uA = h2b[sA * 40 + cl];
        float aB = a_src[sB];
        unsigned int uB = h2b[sB * 40 + cl];
        for (int i = 0; i < cc; ++i) {
            int iC = i + 2; iC = (iC < cc) ? iC : (cc - 1);
            int sC = __builtin_amdgcn_readlane(colreg, iC);
            float aC = a_src[sC];
            unsigned int uC = h2b[sC * 40 + cl];
            float ev = __expf(lrelu(aA + ad));
            den += ev;
            acc = fmaf(ev, __uint_as_float(uA << 16), acc);
            aA = aB; uA = uB;
            aB = aC; uB = uC;
        }
        c += cc;
    }
    if (lane < 40)
        out[(size_t)node * 40 + lane] = acc / (den + 1e-16f) + bias2[lane];
}

// ---------------------------------------------------------------------------
extern "C" void kernel_launch(void* const* d_in, const int* in_sizes, int n_in,
                              void* d_out, int out_size, void* d_ws, size_t ws_size,
                              hipStream_t stream) {
    const float* x   = (const float*)d_in[0];
    const int*   ei  = (const int*)d_in[1];
    const float* W1  = (const float*)d_in[2];
    const float* as1 = (const float*)d_in[3];
    const float* ad1 = (const float*)d_in[4];
    const float* b1  = (const float*)d_in[5];
    const float* W2  = (const float*)d_in[6];
    const float* as2 = (const float*)d_in[7];
    const float* ad2 = (const float*)d_in[8];
    const float* b2  = (const float*)d_in[9];

    int N = in_sizes[0] / 128;
    int E = in_sizes[1] / 2;
    int EN = E + N;
    size_t Np = (size_t)((N + 3) & ~3);

    float* ws = (float*)d_ws;
    float* out1    = ws; ws += Np * 128;
    unsigned int* h1b = (unsigned int*)ws; ws += Np * 64;   // bf16x2 per uint
    unsigned int* h2b = (unsigned int*)ws; ws += Np * 20;
    float* a_src1  = ws; ws += Np * 8;
    float* a_dst1  = ws; ws += Np * 8;
    float* a_src2v = ws; ws += Np;
    float* a_dst2v = ws; ws += Np;
    int* cnt    = (int*)ws; ws += Np;
    int* cur    = (int*)ws; ws += Np;
    int* rowptr = (int*)ws; ws += Np;
    int* psum   = (int*)ws; ws += 256;
    int* col    = (int*)ws; ws += ((size_t)EN + 3) & ~3;

    int nb = (N + 1023) / 1024;  // scan blocks (<=256)

    k_init<<<256, 256, 0, stream>>>(cnt, cur, N);
    k_hist<<<(EN + 255) / 256, 256, 0, stream>>>(ei, E, N, cnt);
    k_scan_part<<<nb, 256, 0, stream>>>(cnt, N, psum);
    k_scan_mid<<<1, 256, 0, stream>>>(psum, nb);
    k_scan_add<<<nb, 256, 0, stream>>>(cnt, N, psum, rowptr);
    k_scatter<<<(EN + 255) / 256, 256, 0, stream>>>(ei, E, N, rowptr, cur, col);

    k_gemm1<<<(N + 15) / 16, 256, 0, stream>>>(x, W1, as1, ad1, h1b, a_src1, a_dst1, N);
    k_aggr1<<<(N + 3) / 4, 256, 0, stream>>>(rowptr, cnt, col, a_src1, a_dst1, h1b, b1, out1, N);
    k_gemm2<<<(N + 255) / 256, 256, 0, stream>>>(out1, W2, as2, ad2, h2b, a_src2v, a_dst2v, N);
    k_aggr2<<<(N + 3) / 4, 256, 0, stream>>>(rowptr, cnt, col, a_src2v, a_dst2v,
                                             (const unsigned short*)h2b, b2, (float*)d_out, N);
}

// Round 6
// 359.066 us; speedup vs baseline: 22.9119x; 1.0769x over previous
//
#include <hip/hip_runtime.h>
#include <hip/hip_bf16.h>
#include <math.h>

#define NEG_SLOPE 0.2f

__device__ __forceinline__ float lrelu(float x) { return x > 0.f ? x : NEG_SLOPE * x; }

// pack two fp32 -> one uint holding 2 bf16 (RNE)
__device__ __forceinline__ unsigned int pack_bf2(float a, float b) {
    unsigned int ua = __float_as_uint(a);
    ua = (ua + 0x7fffu + ((ua >> 16) & 1u)) >> 16;
    unsigned int ub = __float_as_uint(b);
    ub = (ub + 0x7fffu + ((ub >> 16) & 1u)) & 0xffff0000u;
    return ua | ub;
}
__device__ __forceinline__ float bf_lo(unsigned int u) { return __uint_as_float(u << 16); }
__device__ __forceinline__ float bf_hi(unsigned int u) { return __uint_as_float(u & 0xffff0000u); }

// ---------------------------------------------------------------------------
// init: zero cnt + cursor (int)
// ---------------------------------------------------------------------------
__global__ __launch_bounds__(256) void k_init(int* __restrict__ cnt, int* __restrict__ cur, int N) {
    int i = blockIdx.x * 256 + threadIdx.x;
    int stride = gridDim.x * 256;
    for (int j = i; j < N; j += stride) { cnt[j] = 0; cur[j] = 0; }
}

// ---------------------------------------------------------------------------
// histogram of dst (incl. self-loops)
// ---------------------------------------------------------------------------
__global__ __launch_bounds__(256) void k_hist(const int* __restrict__ ei, int E, int N,
                                              int* __restrict__ cnt) {
    int e = blockIdx.x * 256 + threadIdx.x;
    if (e >= E + N) return;
    int d = (e < E) ? ei[E + e] : (e - E);
    atomicAdd(&cnt[d], 1);
}

// ---------------------------------------------------------------------------
// 3-stage exclusive scan of cnt[N] -> rowptr[N]; chunk = 1024 per block
// ---------------------------------------------------------------------------
__global__ __launch_bounds__(256) void k_scan_part(const int* __restrict__ cnt, int N,
                                                   int* __restrict__ psum) {
    __shared__ int sh[256];
    int t = threadIdx.x;
    int base = blockIdx.x * 1024 + t * 4;
    int tl = 0;
#pragma unroll
    for (int j = 0; j < 4; ++j) tl += (base + j < N) ? cnt[base + j] : 0;
    sh[t] = tl; __syncthreads();
    for (int off = 128; off > 0; off >>= 1) {
        if (t < off) sh[t] += sh[t + off];
        __syncthreads();
    }
    if (t == 0) psum[blockIdx.x] = sh[0];
}

__global__ __launch_bounds__(256) void k_scan_mid(int* __restrict__ psum, int nb) {
    __shared__ int sh[256];
    int t = threadIdx.x;
    int v = (t < nb) ? psum[t] : 0;
    sh[t] = v; __syncthreads();
    for (int off = 1; off < 256; off <<= 1) {
        int a = (t >= off) ? sh[t - off] : 0;
        __syncthreads();
        sh[t] += a;
        __syncthreads();
    }
    psum[t] = sh[t] - v;  // exclusive
}

__global__ __launch_bounds__(256) void k_scan_add(const int* __restrict__ cnt, int N,
                                                  const int* __restrict__ psum,
                                                  int* __restrict__ rowptr) {
    __shared__ int sh[256];
    int t = threadIdx.x;
    int base = blockIdx.x * 1024 + t * 4;
    int c[4]; int tl = 0;
#pragma unroll
    for (int j = 0; j < 4; ++j) { c[j] = (base + j < N) ? cnt[base + j] : 0; tl += c[j]; }
    sh[t] = tl; __syncthreads();
    for (int off = 1; off < 256; off <<= 1) {
        int a = (t >= off) ? sh[t - off] : 0;
        __syncthreads();
        sh[t] += a;
        __syncthreads();
    }
    int run = psum[blockIdx.x] + (sh[t] - tl);
#pragma unroll
    for (int j = 0; j < 4; ++j) {
        if (base + j < N) { rowptr[base + j] = run; run += c[j]; }
    }
}

// ---------------------------------------------------------------------------
// scatter src into CSR by dst
// ---------------------------------------------------------------------------
__global__ __launch_bounds__(256) void k_scatter(const int* __restrict__ ei, int E, int N,
                                                 const int* __restrict__ rowptr,
                                                 int* __restrict__ cur,
                                                 int* __restrict__ col) {
    int e = blockIdx.x * 256 + threadIdx.x;
    if (e >= E + N) return;
    int s, d;
    if (e < E) { s = ei[e]; d = ei[E + e]; } else { s = d = e - E; }
    int pos = rowptr[d] + atomicAdd(&cur[d], 1);
    col[pos] = s;
}

// ---------------------------------------------------------------------------
// GEMM1: h1 = x @ W1 ([N,128]@[128,128]). Register-tiled: block = 64 rows x
// 128 cols, thread = 4 rows x 8 cols (32 acc). W staged in LDS in two K=64
// chunks (32 KB -> ~5 blocks/CU); x read from global (L1 broadcast).
// Emits packed-bf16 h1 rows + fused fp32 a_src1/a_dst1.
// ---------------------------------------------------------------------------
__global__ __launch_bounds__(256) void k_gemm1(const float* __restrict__ x,
                                               const float* __restrict__ W,
                                               const float* __restrict__ att_s,
                                               const float* __restrict__ att_d,
                                               unsigned int* __restrict__ h1b,  // [N][64] uints
                                               float* __restrict__ a_src,
                                               float* __restrict__ a_dst, int N) {
    __shared__ float Wc[64 * 128];   // 32 KB K-chunk
    int t = threadIdx.x;
    int rg = t >> 4;           // 0..15 row group
    int cg = t & 15;           // 0..15 col group
    int row0 = blockIdx.x * 64 + rg * 4;
    int col0 = cg * 8;

    // clamped source rows (stores are guarded)
    const float* xr[4];
#pragma unroll
    for (int j = 0; j < 4; ++j) {
        int r = row0 + j; r = (r < N) ? r : (N - 1);
        xr[j] = x + (size_t)r * 128;
    }

    float acc[4][8];
#pragma unroll
    for (int j = 0; j < 4; ++j)
#pragma unroll
        for (int c = 0; c < 8; ++c) acc[j][c] = 0.f;

    for (int kc = 0; kc < 2; ++kc) {
        __syncthreads();
        // stage W rows [kc*64, kc*64+64) : 8 float4 per thread
#pragma unroll
        for (int i = 0; i < 8; ++i) {
            int off = t * 4 + i * 1024;
            *(float4*)&Wc[off] = *(const float4*)&W[kc * 64 * 128 + off];
        }
        __syncthreads();

        for (int k0 = 0; k0 < 64; k0 += 4) {
            int kg = kc * 64 + k0;
            float4 xv[4];
#pragma unroll
            for (int j = 0; j < 4; ++j) xv[j] = *(const float4*)&xr[j][kg];
#pragma unroll
            for (int jj = 0; jj < 4; ++jj) {
                float4 w0 = *(const float4*)&Wc[(k0 + jj) * 128 + col0];
                float4 w1 = *(const float4*)&Wc[(k0 + jj) * 128 + col0 + 4];
#pragma unroll
                for (int j = 0; j < 4; ++j) {
                    float xs = (&xv[j].x)[jj];
                    acc[j][0] = fmaf(xs, w0.x, acc[j][0]);
                    acc[j][1] = fmaf(xs, w0.y, acc[j][1]);
                    acc[j][2] = fmaf(xs, w0.z, acc[j][2]);
                    acc[j][3] = fmaf(xs, w0.w, acc[j][3]);
                    acc[j][4] = fmaf(xs, w1.x, acc[j][4]);
                    acc[j][5] = fmaf(xs, w1.y, acc[j][5]);
                    acc[j][6] = fmaf(xs, w1.z, acc[j][6]);
                    acc[j][7] = fmaf(xs, w1.w, acc[j][7]);
                }
            }
        }
    }

    // epilogue: packed bf16 store + fused attention logits
    float as8[8], ad8[8];
#pragma unroll
    for (int c = 0; c < 8; ++c) { as8[c] = att_s[col0 + c]; ad8[c] = att_d[col0 + c]; }
#pragma unroll
    for (int j = 0; j < 4; ++j) {
        int g = row0 + j;
        float ps = 0.f, pd = 0.f;
#pragma unroll
        for (int c = 0; c < 8; ++c) {
            ps = fmaf(acc[j][c], as8[c], ps);
            pd = fmaf(acc[j][c], ad8[c], pd);
        }
        ps += __shfl_xor(ps, 1);
        pd += __shfl_xor(pd, 1);
        if (g < N) {
            uint4 p = make_uint4(pack_bf2(acc[j][0], acc[j][1]), pack_bf2(acc[j][2], acc[j][3]),
                                 pack_bf2(acc[j][4], acc[j][5]), pack_bf2(acc[j][6], acc[j][7]));
            *(uint4*)&h1b[(size_t)g * 64 + cg * 4] = p;
            if ((t & 1) == 0) {
                int head = cg >> 1;
                a_src[(size_t)g * 8 + head] = ps;
                a_dst[(size_t)g * 8 + head] = pd;
            }
        }
    }
}

// ---------------------------------------------------------------------------
// Layer-1 aggregation: one wave per dst node. Lane l owns channels 2l,2l+1
// (one bf16x2 uint per lane, head = l>>3). Scalar-index scheme via readlane.
// Depth-2 value pipeline. Writes finalized fp32 out1 = num/denom + bias1.
// ---------------------------------------------------------------------------
__global__ __launch_bounds__(256) void k_aggr1(const int* __restrict__ rowptr,
                                               const int* __restrict__ cnt,
                                               const int* __restrict__ col,
                                               const float* __restrict__ a_src,
                                               const float* __restrict__ a_dst,
                                               const unsigned int* __restrict__ h1b,
                                               const float* __restrict__ bias1,
                                               float* __restrict__ out1, int N) {
    int t = threadIdx.x;
    int node = blockIdx.x * 4 + (t >> 6);
    int lane = t & 63;
    if (node >= N) return;
    int beg = rowptr[node];
    int deg = cnt[node];
    int h = lane >> 3;
    float adh = a_dst[node * 8 + h];

    float den = 0.f, n0 = 0.f, n1 = 0.f;
    int c = 0;
    while (c < deg) {
        int cc = deg - c; cc = (cc < 64) ? cc : 64;
        int colreg = col[beg + c + ((lane < cc) ? lane : (cc - 1))];
        int sA = __builtin_amdgcn_readlane(colreg, 0);
        int iB = (cc > 1) ? 1 : 0;
        int sB = __builtin_amdgcn_readlane(colreg, iB);
        float aA = a_src[sA * 8 + h];
        unsigned int uA = h1b[(sA << 6) + lane];
        float aB = a_src[sB * 8 + h];
        unsigned int uB = h1b[(sB << 6) + lane];
        for (int i = 0; i < cc; ++i) {
            int iC = i + 2; iC = (iC < cc) ? iC : (cc - 1);
            int sC = __builtin_amdgcn_readlane(colreg, iC);
            float aC = a_src[sC * 8 + h];
            unsigned int uC = h1b[(sC << 6) + lane];
            float ev = __expf(lrelu(aA + adh));
            den += ev;
            n0 = fmaf(ev, bf_lo(uA), n0);
            n1 = fmaf(ev, bf_hi(uA), n1);
            aA = aB; uA = uB;
            aB = aC; uB = uC;
        }
        c += cc;
    }
    float inv = 1.f / (den + 1e-16f);
    float2 b = *(const float2*)&bias1[2 * lane];
    float2 o = make_float2(fmaf(n0, inv, b.x), fmaf(n1, inv, b.y));
    *(float2*)&out1[(size_t)node * 128 + 2 * lane] = o;
}

// ---------------------------------------------------------------------------
// GEMM2: h2 = out1 @ W2 ([N,128]@[128,40]); emits h2 as packed bf16 rows
// (80 B/row) + fused fp32 a_src2/a_dst2.
// ---------------------------------------------------------------------------
__global__ __launch_bounds__(256) void k_gemm2(const float* __restrict__ out1,
                                               const float* __restrict__ W2,
                                               const float* __restrict__ att_s2,
                                               const float* __restrict__ att_d2,
                                               unsigned int* __restrict__ h2b,  // [N][20] uints
                                               float* __restrict__ a_src2,
                                               float* __restrict__ a_dst2, int N) {
    __shared__ float Ws[128 * 40];
    int t = threadIdx.x;
    for (int i = t * 4; i < 128 * 40; i += 256 * 4)
        *(float4*)&Ws[i] = *(const float4*)&W2[i];
    __syncthreads();
    int n = blockIdx.x * 256 + t;
    if (n >= N) return;

    float acc[40];
#pragma unroll
    for (int c = 0; c < 40; ++c) acc[c] = 0.f;

    for (int k0 = 0; k0 < 128; k0 += 4) {
        float4 v = *(const float4*)&out1[(size_t)n * 128 + k0];
        float xj[4] = {v.x, v.y, v.z, v.w};
#pragma unroll
        for (int j = 0; j < 4; ++j) {
            float xb = xj[j];
#pragma unroll
            for (int c0 = 0; c0 < 40; c0 += 4) {
                float4 w = *(const float4*)&Ws[(k0 + j) * 40 + c0];
                acc[c0 + 0] = fmaf(xb, w.x, acc[c0 + 0]);
                acc[c0 + 1] = fmaf(xb, w.y, acc[c0 + 1]);
                acc[c0 + 2] = fmaf(xb, w.z, acc[c0 + 2]);
                acc[c0 + 3] = fmaf(xb, w.w, acc[c0 + 3]);
            }
        }
    }
    float s2 = 0.f, d2 = 0.f;
#pragma unroll
    for (int c = 0; c < 40; ++c) {
        s2 = fmaf(acc[c], att_s2[c], s2);
        d2 = fmaf(acc[c], att_d2[c], d2);
    }
    unsigned int p[20];
#pragma unroll
    for (int j = 0; j < 20; ++j) p[j] = pack_bf2(acc[2 * j], acc[2 * j + 1]);
#pragma unroll
    for (int j = 0; j < 5; ++j)
        *(uint4*)&h2b[(size_t)n * 20 + 4 * j] = make_uint4(p[4 * j], p[4 * j + 1], p[4 * j + 2], p[4 * j + 3]);
    a_src2[n] = s2;
    a_dst2[n] = d2;
}

// ---------------------------------------------------------------------------
// Layer-2 aggregation: one wave per dst node (H=1, C=40). Scalar-index
// scheme via readlane; a_src[s] is a scalar load; depth-2 pipeline.
// Writes final output (+bias2) directly.
// ---------------------------------------------------------------------------
__global__ __launch_bounds__(256) void k_aggr2(const int* __restrict__ rowptr,
                                               const int* __restrict__ cnt,
                                               const int* __restrict__ col,
                                               const float* __restrict__ a_src,
                                               const float* __restrict__ a_dst,
                                               const unsigned short* __restrict__ h2b,
                                               const float* __restrict__ bias2,
                                               float* __restrict__ out, int N) {
    int t = threadIdx.x;
    int node = blockIdx.x * 4 + (t >> 6);
    int lane = t & 63;
    if (node >= N) return;
    int beg = rowptr[node];
    int deg = cnt[node];
    int cl = (lane < 40) ? lane : 39;
    float ad = a_dst[node];

    float den = 0.f, acc = 0.f;
    int c = 0;
    while (c < deg) {
        int cc = deg - c; cc = (cc < 64) ? cc : 64;
        int colreg = col[beg + c + ((lane < cc) ? lane : (cc - 1))];
        int sA = __builtin_amdgcn_readlane(colreg, 0);
        int iB = (cc > 1) ? 1 : 0;
        int sB = __builtin_amdgcn_readlane(colreg, iB);
        float aA = a_src[sA];
        unsigned int uA = h2b[sA * 40 + cl];
        float aB = a_src[sB];
        unsigned int uB = h2b[sB * 40 + cl];
        for (int i = 0; i < cc; ++i) {
            int iC = i + 2; iC = (iC < cc) ? iC : (cc - 1);
            int sC = __builtin_amdgcn_readlane(colreg, iC);
            float aC = a_src[sC];
            unsigned int uC = h2b[sC * 40 + cl];
            float ev = __expf(lrelu(aA + ad));
            den += ev;
            acc = fmaf(ev, __uint_as_float(uA << 16), acc);
            aA = aB; uA = uB;
            aB = aC; uB = uC;
        }
        c += cc;
    }
    if (lane < 40)
        out[(size_t)node * 40 + lane] = acc / (den + 1e-16f) + bias2[lane];
}

// ---------------------------------------------------------------------------
extern "C" void kernel_launch(void* const* d_in, const int* in_sizes, int n_in,
                              void* d_out, int out_size, void* d_ws, size_t ws_size,
                              hipStream_t stream) {
    const float* x   = (const float*)d_in[0];
    const int*   ei  = (const int*)d_in[1];
    const float* W1  = (const float*)d_in[2];
    const float* as1 = (const float*)d_in[3];
    const float* ad1 = (const float*)d_in[4];
    const float* b1  = (const float*)d_in[5];
    const float* W2  = (const float*)d_in[6];
    const float* as2 = (const float*)d_in[7];
    const float* ad2 = (const float*)d_in[8];
    const float* b2  = (const float*)d_in[9];

    int N = in_sizes[0] / 128;
    int E = in_sizes[1] / 2;
    int EN = E + N;
    size_t Np = (size_t)((N + 3) & ~3);

    float* ws = (float*)d_ws;
    float* out1    = ws; ws += Np * 128;
    unsigned int* h1b = (unsigned int*)ws; ws += Np * 64;   // bf16x2 per uint
    unsigned int* h2b = (unsigned int*)ws; ws += Np * 20;
    float* a_src1  = ws; ws += Np * 8;
    float* a_dst1  = ws; ws += Np * 8;
    float* a_src2v = ws; ws += Np;
    float* a_dst2v = ws; ws += Np;
    int* cnt    = (int*)ws; ws += Np;
    int* cur    = (int*)ws; ws += Np;
    int* rowptr = (int*)ws; ws += Np;
    int* psum   = (int*)ws; ws += 256;
    int* col    = (int*)ws; ws += ((size_t)EN + 3) & ~3;

    int nb = (N + 1023) / 1024;  // scan blocks (<=256)

    k_init<<<256, 256, 0, stream>>>(cnt, cur, N);
    k_hist<<<(EN + 255) / 256, 256, 0, stream>>>(ei, E, N, cnt);
    k_scan_part<<<nb, 256, 0, stream>>>(cnt, N, psum);
    k_scan_mid<<<1, 256, 0, stream>>>(psum, nb);
    k_scan_add<<<nb, 256, 0, stream>>>(cnt, N, psum, rowptr);
    k_scatter<<<(EN + 255) / 256, 256, 0, stream>>>(ei, E, N, rowptr, cur, col);

    k_gemm1<<<(N + 63) / 64, 256, 0, stream>>>(x, W1, as1, ad1, h1b, a_src1, a_dst1, N);
    k_aggr1<<<(N + 3) / 4, 256, 0, stream>>>(rowptr, cnt, col, a_src1, a_dst1, h1b, b1, out1, N);
    k_gemm2<<<(N + 255) / 256, 256, 0, stream>>>(out1, W2, as2, ad2, h2b, a_src2v, a_dst2v, N);
    k_aggr2<<<(N + 3) / 4, 256, 0, stream>>>(rowptr, cnt, col, a_src2v, a_dst2v,
                                             (const unsigned short*)h2b, b2, (float*)d_out, N);
}

// Round 7
// 322.561 us; speedup vs baseline: 25.5049x; 1.1132x over previous
//
#include <hip/hip_runtime.h>
#include <hip/hip_bf16.h>
#include <math.h>

#define NEG_SLOPE 0.2f

__device__ __forceinline__ float lrelu(float x) { return x > 0.f ? x : NEG_SLOPE * x; }

// pack two fp32 -> one uint holding 2 bf16 (RNE)
__device__ __forceinline__ unsigned int pack_bf2(float a, float b) {
    unsigned int ua = __float_as_uint(a);
    ua = (ua + 0x7fffu + ((ua >> 16) & 1u)) >> 16;
    unsigned int ub = __float_as_uint(b);
    ub = (ub + 0x7fffu + ((ub >> 16) & 1u)) & 0xffff0000u;
    return ua | ub;
}
__device__ __forceinline__ float bf_lo(unsigned int u) { return __uint_as_float(u << 16); }
__device__ __forceinline__ float bf_hi(unsigned int u) { return __uint_as_float(u & 0xffff0000u); }
__device__ __forceinline__ float rdlane_f(float v, int i) {
    return __int_as_float(__builtin_amdgcn_readlane(__float_as_int(v), i));
}

// ---------------------------------------------------------------------------
// histogram of dst (incl. self-loops); also emits rank[e] = arrival order
// ---------------------------------------------------------------------------
__global__ __launch_bounds__(256) void k_hist(const int* __restrict__ ei, int E, int N,
                                              int* __restrict__ cnt, int* __restrict__ rank) {
    int e = blockIdx.x * 256 + threadIdx.x;
    if (e >= E + N) return;
    int d = (e < E) ? ei[E + e] : (e - E);
    rank[e] = atomicAdd(&cnt[d], 1);
}

// ---------------------------------------------------------------------------
// 3-stage exclusive scan of cnt[N] -> rowptr[N]; chunk = 1024 per block
// ---------------------------------------------------------------------------
__global__ __launch_bounds__(256) void k_scan_part(const int* __restrict__ cnt, int N,
                                                   int* __restrict__ psum) {
    __shared__ int sh[256];
    int t = threadIdx.x;
    int base = blockIdx.x * 1024 + t * 4;
    int tl = 0;
#pragma unroll
    for (int j = 0; j < 4; ++j) tl += (base + j < N) ? cnt[base + j] : 0;
    sh[t] = tl; __syncthreads();
    for (int off = 128; off > 0; off >>= 1) {
        if (t < off) sh[t] += sh[t + off];
        __syncthreads();
    }
    if (t == 0) psum[blockIdx.x] = sh[0];
}

__global__ __launch_bounds__(256) void k_scan_mid(int* __restrict__ psum, int nb) {
    __shared__ int sh[256];
    int t = threadIdx.x;
    int v = (t < nb) ? psum[t] : 0;
    sh[t] = v; __syncthreads();
    for (int off = 1; off < 256; off <<= 1) {
        int a = (t >= off) ? sh[t - off] : 0;
        __syncthreads();
        sh[t] += a;
        __syncthreads();
    }
    psum[t] = sh[t] - v;  // exclusive
}

__global__ __launch_bounds__(256) void k_scan_add(const int* __restrict__ cnt, int N,
                                                  const int* __restrict__ psum,
                                                  int* __restrict__ rowptr) {
    __shared__ int sh[256];
    int t = threadIdx.x;
    int base = blockIdx.x * 1024 + t * 4;
    int c[4]; int tl = 0;
#pragma unroll
    for (int j = 0; j < 4; ++j) { c[j] = (base + j < N) ? cnt[base + j] : 0; tl += c[j]; }
    sh[t] = tl; __syncthreads();
    for (int off = 1; off < 256; off <<= 1) {
        int a = (t >= off) ? sh[t - off] : 0;
        __syncthreads();
        sh[t] += a;
        __syncthreads();
    }
    int run = psum[blockIdx.x] + (sh[t] - tl);
#pragma unroll
    for (int j = 0; j < 4; ++j) {
        if (base + j < N) { rowptr[base + j] = run; run += c[j]; }
    }
}

// ---------------------------------------------------------------------------
// scatter src into CSR by dst using precomputed rank (no atomics)
// ---------------------------------------------------------------------------
__global__ __launch_bounds__(256) void k_scatter(const int* __restrict__ ei, int E, int N,
                                                 const int* __restrict__ rowptr,
                                                 const int* __restrict__ rank,
                                                 int* __restrict__ col) {
    int e = blockIdx.x * 256 + threadIdx.x;
    if (e >= E + N) return;
    int s, d;
    if (e < E) { s = ei[e]; d = ei[E + e]; } else { s = d = e - E; }
    col[rowptr[d] + rank[e]] = s;
}

// ---------------------------------------------------------------------------
// GEMM1: h1 = x @ W1 ([N,128]@[128,128]). Register-tiled: block = 64 rows x
// 128 cols, thread = 4 rows x 8 cols. W staged in LDS in two K=64 chunks.
// Emits packed-bf16 h1 rows + fused fp32 a_src1/a_dst1.
// ---------------------------------------------------------------------------
__global__ __launch_bounds__(256) void k_gemm1(const float* __restrict__ x,
                                               const float* __restrict__ W,
                                               const float* __restrict__ att_s,
                                               const float* __restrict__ att_d,
                                               unsigned int* __restrict__ h1b,  // [N][64] uints
                                               float* __restrict__ a_src,
                                               float* __restrict__ a_dst, int N) {
    __shared__ float Wc[64 * 128];   // 32 KB K-chunk
    int t = threadIdx.x;
    int rg = t >> 4;           // 0..15 row group
    int cg = t & 15;           // 0..15 col group
    int row0 = blockIdx.x * 64 + rg * 4;
    int col0 = cg * 8;

    const float* xr[4];
#pragma unroll
    for (int j = 0; j < 4; ++j) {
        int r = row0 + j; r = (r < N) ? r : (N - 1);
        xr[j] = x + (size_t)r * 128;
    }

    float acc[4][8];
#pragma unroll
    for (int j = 0; j < 4; ++j)
#pragma unroll
        for (int c = 0; c < 8; ++c) acc[j][c] = 0.f;

    for (int kc = 0; kc < 2; ++kc) {
        __syncthreads();
#pragma unroll
        for (int i = 0; i < 8; ++i) {
            int off = t * 4 + i * 1024;
            *(float4*)&Wc[off] = *(const float4*)&W[kc * 64 * 128 + off];
        }
        __syncthreads();

        for (int k0 = 0; k0 < 64; k0 += 4) {
            int kg = kc * 64 + k0;
            float4 xv[4];
#pragma unroll
            for (int j = 0; j < 4; ++j) xv[j] = *(const float4*)&xr[j][kg];
#pragma unroll
            for (int jj = 0; jj < 4; ++jj) {
                float4 w0 = *(const float4*)&Wc[(k0 + jj) * 128 + col0];
                float4 w1 = *(const float4*)&Wc[(k0 + jj) * 128 + col0 + 4];
#pragma unroll
                for (int j = 0; j < 4; ++j) {
                    float xs = (&xv[j].x)[jj];
                    acc[j][0] = fmaf(xs, w0.x, acc[j][0]);
                    acc[j][1] = fmaf(xs, w0.y, acc[j][1]);
                    acc[j][2] = fmaf(xs, w0.z, acc[j][2]);
                    acc[j][3] = fmaf(xs, w0.w, acc[j][3]);
                    acc[j][4] = fmaf(xs, w1.x, acc[j][4]);
                    acc[j][5] = fmaf(xs, w1.y, acc[j][5]);
                    acc[j][6] = fmaf(xs, w1.z, acc[j][6]);
                    acc[j][7] = fmaf(xs, w1.w, acc[j][7]);
                }
            }
        }
    }

    float as8[8], ad8[8];
#pragma unroll
    for (int c = 0; c < 8; ++c) { as8[c] = att_s[col0 + c]; ad8[c] = att_d[col0 + c]; }
#pragma unroll
    for (int j = 0; j < 4; ++j) {
        int g = row0 + j;
        float ps = 0.f, pd = 0.f;
#pragma unroll
        for (int c = 0; c < 8; ++c) {
            ps = fmaf(acc[j][c], as8[c], ps);
            pd = fmaf(acc[j][c], ad8[c], pd);
        }
        ps += __shfl_xor(ps, 1);
        pd += __shfl_xor(pd, 1);
        if (g < N) {
            uint4 p = make_uint4(pack_bf2(acc[j][0], acc[j][1]), pack_bf2(acc[j][2], acc[j][3]),
                                 pack_bf2(acc[j][4], acc[j][5]), pack_bf2(acc[j][6], acc[j][7]));
            *(uint4*)&h1b[(size_t)g * 64 + cg * 4] = p;
            if ((t & 1) == 0) {
                int head = cg >> 1;
                a_src[(size_t)g * 8 + head] = ps;
                a_dst[(size_t)g * 8 + head] = pd;
            }
        }
    }
}

// ---------------------------------------------------------------------------
// Layer-1 aggregation: one wave per dst node. Per 64-edge chunk, lane i
// computes all 8 head-evs for edge i (coalesced a_src gather, 8 exps) into a
// per-wave LDS strip (stride 9, wave-synchronous). Inner loop: readlane col,
// ds_read ev, saddr h1b gather, 3 fma. Writes out1 = num/den + bias1.
// ---------------------------------------------------------------------------
__global__ __launch_bounds__(256) void k_aggr1(const int* __restrict__ rowptr,
                                               const int* __restrict__ cnt,
                                               const int* __restrict__ col,
                                               const float* __restrict__ a_src,
                                               const float* __restrict__ a_dst,
                                               const unsigned int* __restrict__ h1b,
                                               const float* __restrict__ bias1,
                                               float* __restrict__ out1, int N) {
    __shared__ float evs[4][64 * 9];   // 9216 B, one strip per wave
    int t = threadIdx.x;
    int w = t >> 6;
    int lane = t & 63;
    int node = blockIdx.x * 4 + w;
    if (node >= N) return;
    int beg = rowptr[node];
    int deg = cnt[node];
    int h = lane >> 3;
    float4 ad0 = *(const float4*)&a_dst[(size_t)node * 8];
    float4 ad1 = *(const float4*)&a_dst[(size_t)node * 8 + 4];
    float* myev = &evs[w][0];

    float den = 0.f, n0 = 0.f, n1 = 0.f;
    int c = 0;
    while (c < deg) {
        int cc = deg - c; cc = (cc < 64) ? cc : 64;
        int colreg = col[beg + c + ((lane < cc) ? lane : (cc - 1))];
        // per-lane: compute ev for MY edge, all 8 heads (coalesced gather)
        float4 as0 = *(const float4*)&a_src[(size_t)colreg * 8];
        float4 as1 = *(const float4*)&a_src[(size_t)colreg * 8 + 4];
        float e0 = __expf(lrelu(as0.x + ad0.x));
        float e1 = __expf(lrelu(as0.y + ad0.y));
        float e2 = __expf(lrelu(as0.z + ad0.z));
        float e3 = __expf(lrelu(as0.w + ad0.w));
        float e4 = __expf(lrelu(as1.x + ad1.x));
        float e5 = __expf(lrelu(as1.y + ad1.y));
        float e6 = __expf(lrelu(as1.z + ad1.z));
        float e7 = __expf(lrelu(as1.w + ad1.w));
        *(float4*)&myev[lane * 9]     = make_float4(e0, e1, e2, e3);
        *(float4*)&myev[lane * 9 + 4] = make_float4(e4, e5, e6, e7);
        // wave-synchronous LDS: no barrier needed (single wave producer/consumer)

        int sA = __builtin_amdgcn_readlane(colreg, 0);
        unsigned int uA = h1b[(sA << 6) + lane];
        int iB = (cc > 1) ? 1 : 0;
        int sB = __builtin_amdgcn_readlane(colreg, iB);
        unsigned int uB = h1b[(sB << 6) + lane];
        for (int i = 0; i < cc; ++i) {
            int iC = i + 2; iC = (iC < cc) ? iC : (cc - 1);
            int sC = __builtin_amdgcn_readlane(colreg, iC);
            unsigned int uC = h1b[(sC << 6) + lane];
            float ev = myev[i * 9 + h];
            den += ev;
            n0 = fmaf(ev, bf_lo(uA), n0);
            n1 = fmaf(ev, bf_hi(uA), n1);
            uA = uB; uB = uC;
        }
        c += cc;
    }
    float inv = 1.f / (den + 1e-16f);
    float2 b = *(const float2*)&bias1[2 * lane];
    float2 o = make_float2(fmaf(n0, inv, b.x), fmaf(n1, inv, b.y));
    *(float2*)&out1[(size_t)node * 128 + 2 * lane] = o;
}

// ---------------------------------------------------------------------------
// GEMM2: h2 = out1 @ W2 ([N,128]@[128,40]); emits h2 as packed bf16 rows
// (80 B/row) + fused fp32 a_src2/a_dst2.
// ---------------------------------------------------------------------------
__global__ __launch_bounds__(256) void k_gemm2(const float* __restrict__ out1,
                                               const float* __restrict__ W2,
                                               const float* __restrict__ att_s2,
                                               const float* __restrict__ att_d2,
                                               unsigned int* __restrict__ h2b,  // [N][20] uints
                                               float* __restrict__ a_src2,
                                               float* __restrict__ a_dst2, int N) {
    __shared__ float Ws[128 * 40];
    int t = threadIdx.x;
    for (int i = t * 4; i < 128 * 40; i += 256 * 4)
        *(float4*)&Ws[i] = *(const float4*)&W2[i];
    __syncthreads();
    int n = blockIdx.x * 256 + t;
    if (n >= N) return;

    float acc[40];
#pragma unroll
    for (int c = 0; c < 40; ++c) acc[c] = 0.f;

    for (int k0 = 0; k0 < 128; k0 += 4) {
        float4 v = *(const float4*)&out1[(size_t)n * 128 + k0];
        float xj[4] = {v.x, v.y, v.z, v.w};
#pragma unroll
        for (int j = 0; j < 4; ++j) {
            float xb = xj[j];
#pragma unroll
            for (int c0 = 0; c0 < 40; c0 += 4) {
                float4 w = *(const float4*)&Ws[(k0 + j) * 40 + c0];
                acc[c0 + 0] = fmaf(xb, w.x, acc[c0 + 0]);
                acc[c0 + 1] = fmaf(xb, w.y, acc[c0 + 1]);
                acc[c0 + 2] = fmaf(xb, w.z, acc[c0 + 2]);
                acc[c0 + 3] = fmaf(xb, w.w, acc[c0 + 3]);
            }
        }
    }
    float s2 = 0.f, d2 = 0.f;
#pragma unroll
    for (int c = 0; c < 40; ++c) {
        s2 = fmaf(acc[c], att_s2[c], s2);
        d2 = fmaf(acc[c], att_d2[c], d2);
    }
    unsigned int p[20];
#pragma unroll
    for (int j = 0; j < 20; ++j) p[j] = pack_bf2(acc[2 * j], acc[2 * j + 1]);
#pragma unroll
    for (int j = 0; j < 5; ++j)
        *(uint4*)&h2b[(size_t)n * 20 + 4 * j] = make_uint4(p[4 * j], p[4 * j + 1], p[4 * j + 2], p[4 * j + 3]);
    a_src2[n] = s2;
    a_dst2[n] = d2;
}

// ---------------------------------------------------------------------------
// Layer-2 aggregation: one wave per dst node (H=1, C=40). Per 64-edge chunk,
// lane i computes ev for edge i once (coalesced); inner loop broadcasts ev
// via readlane (register-resident), den += scalar, saddr h2b gather.
// Writes final output (+bias2) directly.
// ---------------------------------------------------------------------------
__global__ __launch_bounds__(256) void k_aggr2(const int* __restrict__ rowptr,
                                               const int* __restrict__ cnt,
                                               const int* __restrict__ col,
                                               const float* __restrict__ a_src,
                                               const float* __restrict__ a_dst,
                                               const unsigned short* __restrict__ h2b,
                                               const float* __restrict__ bias2,
                                               float* __restrict__ out, int N) {
    int t = threadIdx.x;
    int node = blockIdx.x * 4 + (t >> 6);
    int lane = t & 63;
    if (node >= N) return;
    int beg = rowptr[node];
    int deg = cnt[node];
    int cl = (lane < 40) ? lane : 39;
    float ad = a_dst[node];

    float den = 0.f, acc = 0.f;
    int c = 0;
    while (c < deg) {
        int cc = deg - c; cc = (cc < 64) ? cc : 64;
        int colreg = col[beg + c + ((lane < cc) ? lane : (cc - 1))];
        float ev = __expf(lrelu(a_src[colreg] + ad));   // coalesced gather + 1 exp/lane

        int sA = __builtin_amdgcn_readlane(colreg, 0);
        unsigned int uA = h2b[sA * 40 + cl];
        int iB = (cc > 1) ? 1 : 0;
        int sB = __builtin_amdgcn_readlane(colreg, iB);
        unsigned int uB = h2b[sB * 40 + cl];
        for (int i = 0; i < cc; ++i) {
            int iC = i + 2; iC = (iC < cc) ? iC : (cc - 1);
            int sC = __builtin_amdgcn_readlane(colreg, iC);
            unsigned int uC = h2b[sC * 40 + cl];
            float evs_ = rdlane_f(ev, i);
            den += evs_;
            acc = fmaf(evs_, __uint_as_float(uA << 16), acc);
            uA = uB; uB = uC;
        }
        c += cc;
    }
    if (lane < 40)
        out[(size_t)node * 40 + lane] = acc / (den + 1e-16f) + bias2[lane];
}

// ---------------------------------------------------------------------------
extern "C" void kernel_launch(void* const* d_in, const int* in_sizes, int n_in,
                              void* d_out, int out_size, void* d_ws, size_t ws_size,
                              hipStream_t stream) {
    const float* x   = (const float*)d_in[0];
    const int*   ei  = (const int*)d_in[1];
    const float* W1  = (const float*)d_in[2];
    const float* as1 = (const float*)d_in[3];
    const float* ad1 = (const float*)d_in[4];
    const float* b1  = (const float*)d_in[5];
    const float* W2  = (const float*)d_in[6];
    const float* as2 = (const float*)d_in[7];
    const float* ad2 = (const float*)d_in[8];
    const float* b2  = (const float*)d_in[9];

    int N = in_sizes[0] / 128;
    int E = in_sizes[1] / 2;
    int EN = E + N;
    size_t Np = (size_t)((N + 3) & ~3);
    size_t ENp = ((size_t)EN + 3) & ~3;

    float* ws = (float*)d_ws;
    float* out1    = ws; ws += Np * 128;
    unsigned int* h1b = (unsigned int*)ws; ws += Np * 64;   // bf16x2 per uint
    unsigned int* h2b = (unsigned int*)ws; ws += Np * 20;
    float* a_src1  = ws; ws += Np * 8;
    float* a_dst1  = ws; ws += Np * 8;
    float* a_src2v = ws; ws += Np;
    float* a_dst2v = ws; ws += Np;
    int* cnt    = (int*)ws; ws += Np;
    int* rowptr = (int*)ws; ws += Np;
    int* psum   = (int*)ws; ws += 256;
    int* col    = (int*)ws; ws += ENp;
    int* rank   = (int*)ws; ws += ENp;

    int nb = (N + 1023) / 1024;  // scan blocks (<=256)

    hipMemsetAsync(cnt, 0, (size_t)N * sizeof(int), stream);
    k_hist<<<(EN + 255) / 256, 256, 0, stream>>>(ei, E, N, cnt, rank);
    k_scan_part<<<nb, 256, 0, stream>>>(cnt, N, psum);
    k_scan_mid<<<1, 256, 0, stream>>>(psum, nb);
    k_scan_add<<<nb, 256, 0, stream>>>(cnt, N, psum, rowptr);
    k_scatter<<<(EN + 255) / 256, 256, 0, stream>>>(ei, E, N, rowptr, rank, col);

    k_gemm1<<<(N + 63) / 64, 256, 0, stream>>>(x, W1, as1, ad1, h1b, a_src1, a_dst1, N);
    k_aggr1<<<(N + 3) / 4, 256, 0, stream>>>(rowptr, cnt, col, a_src1, a_dst1, h1b, b1, out1, N);
    k_gemm2<<<(N + 255) / 256, 256, 0, stream>>>(out1, W2, as2, ad2, h2b, a_src2v, a_dst2v, N);
    k_aggr2<<<(N + 3) / 4, 256, 0, stream>>>(rowptr, cnt, col, a_src2v, a_dst2v,
                                             (const unsigned short*)h2b, b2, (float*)d_out, N);
}

// Round 8
// 273.959 us; speedup vs baseline: 30.0296x; 1.1774x over previous
//
#include <hip/hip_runtime.h>
#include <hip/hip_bf16.h>
#include <math.h>

#define NEG_SLOPE 0.2f

__device__ __forceinline__ float lrelu(float x) { return x > 0.f ? x : NEG_SLOPE * x; }

// pack two fp32 -> one uint holding 2 bf16 (RNE)
__device__ __forceinline__ unsigned int pack_bf2(float a, float b) {
    unsigned int ua = __float_as_uint(a);
    ua = (ua + 0x7fffu + ((ua >> 16) & 1u)) >> 16;
    unsigned int ub = __float_as_uint(b);
    ub = (ub + 0x7fffu + ((ub >> 16) & 1u)) & 0xffff0000u;
    return ua | ub;
}
__device__ __forceinline__ float bf_lo(unsigned int u) { return __uint_as_float(u << 16); }
__device__ __forceinline__ float bf_hi(unsigned int u) { return __uint_as_float(u & 0xffff0000u); }

// ---------------------------------------------------------------------------
// histogram of dst (incl. self-loops); also emits rank[e] = arrival order
// ---------------------------------------------------------------------------
__global__ __launch_bounds__(256) void k_hist(const int* __restrict__ ei, int E, int N,
                                              int* __restrict__ cnt, int* __restrict__ rank) {
    int e = blockIdx.x * 256 + threadIdx.x;
    if (e >= E + N) return;
    int d = (e < E) ? ei[E + e] : (e - E);
    rank[e] = atomicAdd(&cnt[d], 1);
}

// ---------------------------------------------------------------------------
// 3-stage exclusive scan of cnt[N] -> rowptr[N]; chunk = 1024 per block
// ---------------------------------------------------------------------------
__global__ __launch_bounds__(256) void k_scan_part(const int* __restrict__ cnt, int N,
                                                   int* __restrict__ psum) {
    __shared__ int sh[256];
    int t = threadIdx.x;
    int base = blockIdx.x * 1024 + t * 4;
    int tl = 0;
#pragma unroll
    for (int j = 0; j < 4; ++j) tl += (base + j < N) ? cnt[base + j] : 0;
    sh[t] = tl; __syncthreads();
    for (int off = 128; off > 0; off >>= 1) {
        if (t < off) sh[t] += sh[t + off];
        __syncthreads();
    }
    if (t == 0) psum[blockIdx.x] = sh[0];
}

__global__ __launch_bounds__(256) void k_scan_mid(int* __restrict__ psum, int nb) {
    __shared__ int sh[256];
    int t = threadIdx.x;
    int v = (t < nb) ? psum[t] : 0;
    sh[t] = v; __syncthreads();
    for (int off = 1; off < 256; off <<= 1) {
        int a = (t >= off) ? sh[t - off] : 0;
        __syncthreads();
        sh[t] += a;
        __syncthreads();
    }
    psum[t] = sh[t] - v;  // exclusive
}

__global__ __launch_bounds__(256) void k_scan_add(const int* __restrict__ cnt, int N,
                                                  const int* __restrict__ psum,
                                                  int* __restrict__ rowptr) {
    __shared__ int sh[256];
    int t = threadIdx.x;
    int base = blockIdx.x * 1024 + t * 4;
    int c[4]; int tl = 0;
#pragma unroll
    for (int j = 0; j < 4; ++j) { c[j] = (base + j < N) ? cnt[base + j] : 0; tl += c[j]; }
    sh[t] = tl; __syncthreads();
    for (int off = 1; off < 256; off <<= 1) {
        int a = (t >= off) ? sh[t - off] : 0;
        __syncthreads();
        sh[t] += a;
        __syncthreads();
    }
    int run = psum[blockIdx.x] + (sh[t] - tl);
#pragma unroll
    for (int j = 0; j < 4; ++j) {
        if (base + j < N) { rowptr[base + j] = run; run += c[j]; }
    }
}

// ---------------------------------------------------------------------------
// scatter src into CSR by dst using precomputed rank (no atomics)
// ---------------------------------------------------------------------------
__global__ __launch_bounds__(256) void k_scatter(const int* __restrict__ ei, int E, int N,
                                                 const int* __restrict__ rowptr,
                                                 const int* __restrict__ rank,
                                                 int* __restrict__ col) {
    int e = blockIdx.x * 256 + threadIdx.x;
    if (e >= E + N) return;
    int s, d;
    if (e < E) { s = ei[e]; d = ei[E + e]; } else { s = d = e - E; }
    col[rowptr[d] + rank[e]] = s;
}

// ---------------------------------------------------------------------------
// GEMM1: h1 = x @ W1 ([N,128]@[128,128]). Register-tiled. Emits h1 as two
// channel-split packed-bf16 arrays h1A (ch 0-63) / h1B (ch 64-127), 128 B/row
// each, + fused fp32 a_src1/a_dst1.
// ---------------------------------------------------------------------------
__global__ __launch_bounds__(256) void k_gemm1(const float* __restrict__ x,
                                               const float* __restrict__ W,
                                               const float* __restrict__ att_s,
                                               const float* __restrict__ att_d,
                                               unsigned int* __restrict__ h1A,  // [N][32] uints
                                               unsigned int* __restrict__ h1B,  // [N][32] uints
                                               float* __restrict__ a_src,
                                               float* __restrict__ a_dst, int N) {
    __shared__ float Wc[64 * 128];   // 32 KB K-chunk
    int t = threadIdx.x;
    int rg = t >> 4;           // 0..15 row group
    int cg = t & 15;           // 0..15 col group
    int row0 = blockIdx.x * 64 + rg * 4;
    int col0 = cg * 8;

    const float* xr[4];
#pragma unroll
    for (int j = 0; j < 4; ++j) {
        int r = row0 + j; r = (r < N) ? r : (N - 1);
        xr[j] = x + (size_t)r * 128;
    }

    float acc[4][8];
#pragma unroll
    for (int j = 0; j < 4; ++j)
#pragma unroll
        for (int c = 0; c < 8; ++c) acc[j][c] = 0.f;

    for (int kc = 0; kc < 2; ++kc) {
        __syncthreads();
#pragma unroll
        for (int i = 0; i < 8; ++i) {
            int off = t * 4 + i * 1024;
            *(float4*)&Wc[off] = *(const float4*)&W[kc * 64 * 128 + off];
        }
        __syncthreads();

        for (int k0 = 0; k0 < 64; k0 += 4) {
            int kg = kc * 64 + k0;
            float4 xv[4];
#pragma unroll
            for (int j = 0; j < 4; ++j) xv[j] = *(const float4*)&xr[j][kg];
#pragma unroll
            for (int jj = 0; jj < 4; ++jj) {
                float4 w0 = *(const float4*)&Wc[(k0 + jj) * 128 + col0];
                float4 w1 = *(const float4*)&Wc[(k0 + jj) * 128 + col0 + 4];
#pragma unroll
                for (int j = 0; j < 4; ++j) {
                    float xs = (&xv[j].x)[jj];
                    acc[j][0] = fmaf(xs, w0.x, acc[j][0]);
                    acc[j][1] = fmaf(xs, w0.y, acc[j][1]);
                    acc[j][2] = fmaf(xs, w0.z, acc[j][2]);
                    acc[j][3] = fmaf(xs, w0.w, acc[j][3]);
                    acc[j][4] = fmaf(xs, w1.x, acc[j][4]);
                    acc[j][5] = fmaf(xs, w1.y, acc[j][5]);
                    acc[j][6] = fmaf(xs, w1.z, acc[j][6]);
                    acc[j][7] = fmaf(xs, w1.w, acc[j][7]);
                }
            }
        }
    }

    float as8[8], ad8[8];
#pragma unroll
    for (int c = 0; c < 8; ++c) { as8[c] = att_s[col0 + c]; ad8[c] = att_d[col0 + c]; }
    unsigned int* hp = (cg < 8) ? h1A : h1B;
    int loff = (cg & 7) * 4;
#pragma unroll
    for (int j = 0; j < 4; ++j) {
        int g = row0 + j;
        float ps = 0.f, pd = 0.f;
#pragma unroll
        for (int c = 0; c < 8; ++c) {
            ps = fmaf(acc[j][c], as8[c], ps);
            pd = fmaf(acc[j][c], ad8[c], pd);
        }
        ps += __shfl_xor(ps, 1);
        pd += __shfl_xor(pd, 1);
        if (g < N) {
            uint4 p = make_uint4(pack_bf2(acc[j][0], acc[j][1]), pack_bf2(acc[j][2], acc[j][3]),
                                 pack_bf2(acc[j][4], acc[j][5]), pack_bf2(acc[j][6], acc[j][7]));
            *(uint4*)&hp[(size_t)g * 32 + loff] = p;
            if ((t & 1) == 0) {
                int head = cg >> 1;
                a_src[(size_t)g * 8 + head] = ps;
                a_dst[(size_t)g * 8 + head] = pd;
            }
        }
    }
}

// ---------------------------------------------------------------------------
// Layer-1 aggregation, channel-split pass p (p=0: ch 0-63 / heads 0-3;
// p=1: ch 64-127 / heads 4-7). Footprint per pass = 6.4 MB (fits L2 better).
// Two nodes per wave (32 lanes each); lane u owns channels p*64+2u,2u+1
// (one uint from hp[node][32]). Per 32-edge chunk: lane u computes 4 evs for
// edge u of its half (coalesced a_src float4 gather), stages col+ev in
// per-wave LDS strips (wave-synchronous, no barrier). Inner loop: 2 ds_reads,
// 1 saddr gather, 2 fma per covered edge-pair. den recomputed per pass.
// Writes out1 columns [p*64, p*64+64) = num/den + bias1.
// ---------------------------------------------------------------------------
__global__ __launch_bounds__(256) void k_aggr1(const int* __restrict__ rowptr,
                                               const int* __restrict__ cnt,
                                               const int* __restrict__ col,
                                               const float* __restrict__ a_src,
                                               const float* __restrict__ a_dst,
                                               const unsigned int* __restrict__ hp,
                                               const float* __restrict__ bias1,
                                               float* __restrict__ out1, int N, int p) {
    __shared__ float evs[4][2][128];   // [wave][half][edge*4+head]
    __shared__ int   cls[4][2][32];    // [wave][half][edge]
    int t = threadIdx.x;
    int w = t >> 6;
    int lane = t & 63;
    int half = lane >> 5;
    int u = lane & 31;
    int node = blockIdx.x * 8 + w * 2 + half;
    bool nv = (node < N);
    int nodec = nv ? node : (N - 1);
    int beg = rowptr[nodec];
    int deg = nv ? cnt[nodec] : 0;
    int degO = __shfl_xor(deg, 32);
    int degmax = (deg > degO) ? deg : degO;
    if (degmax <= 0) return;   // uniform across wave

    int hh = u >> 3;                           // phase-local head 0..3
    float adh = a_dst[(size_t)nodec * 8 + p * 4 + hh];
    // per-lane a_dst for ev compute (all 4 phase heads)
    float4 ad4 = *(const float4*)&a_dst[(size_t)nodec * 8 + p * 4];

    float* myev = &evs[w][half][0];
    int*   mycl = &cls[w][half][0];

    float den = 0.f, n0 = 0.f, n1 = 0.f;
    int c = 0;
    while (c < degmax) {
        int slot = c + u;
        int slotc = (slot < deg) ? slot : (deg - 1);
        if (slotc < 0) slotc = 0;
        int su = col[beg + slotc];
        float4 as4 = *(const float4*)&a_src[(size_t)su * 8 + p * 4];
        bool valid = (slot < deg);
        float e0 = valid ? __expf(lrelu(as4.x + ad4.x)) : 0.f;
        float e1 = valid ? __expf(lrelu(as4.y + ad4.y)) : 0.f;
        float e2 = valid ? __expf(lrelu(as4.z + ad4.z)) : 0.f;
        float e3 = valid ? __expf(lrelu(as4.w + ad4.w)) : 0.f;
        *(float4*)&myev[u * 4] = make_float4(e0, e1, e2, e3);
        mycl[u] = su;
        // wave-synchronous LDS: single-wave producer/consumer, no barrier

        int ccm = degmax - c; ccm = (ccm < 32) ? ccm : 32;
        // depth-1 pipeline on (s, gathered uint)
        int sP = mycl[0];
        unsigned int uP = hp[sP * 32 + u];
        for (int i = 0; i < ccm; ++i) {
            int in = (i + 1 < ccm) ? (i + 1) : i;
            int sN = mycl[in];
            unsigned int uN = hp[sN * 32 + u];
            float ev = myev[i * 4 + hh];
            den += ev;
            n0 = fmaf(ev, bf_lo(uP), n0);
            n1 = fmaf(ev, bf_hi(uP), n1);
            uP = uN;
        }
        c += 32;
    }
    if (nv) {
        float inv = 1.f / (den + 1e-16f);
        int ch = p * 64 + 2 * u;
        float2 b = *(const float2*)&bias1[ch];
        float2 o = make_float2(fmaf(n0, inv, b.x), fmaf(n1, inv, b.y));
        *(float2*)&out1[(size_t)node * 128 + ch] = o;
    }
}

// ---------------------------------------------------------------------------
// GEMM2: h2 = out1 @ W2 ([N,128]@[128,40]); emits h2 as packed bf16 rows
// (80 B/row) + fused fp32 a_src2/a_dst2.
// ---------------------------------------------------------------------------
__global__ __launch_bounds__(256) void k_gemm2(const float* __restrict__ out1,
                                               const float* __restrict__ W2,
                                               const float* __restrict__ att_s2,
                                               const float* __restrict__ att_d2,
                                               unsigned int* __restrict__ h2b,  // [N][20] uints
                                               float* __restrict__ a_src2,
                                               float* __restrict__ a_dst2, int N) {
    __shared__ float Ws[128 * 40];
    int t = threadIdx.x;
    for (int i = t * 4; i < 128 * 40; i += 256 * 4)
        *(float4*)&Ws[i] = *(const float4*)&W2[i];
    __syncthreads();
    int n = blockIdx.x * 256 + t;
    if (n >= N) return;

    float acc[40];
#pragma unroll
    for (int c = 0; c < 40; ++c) acc[c] = 0.f;

    for (int k0 = 0; k0 < 128; k0 += 4) {
        float4 v = *(const float4*)&out1[(size_t)n * 128 + k0];
        float xj[4] = {v.x, v.y, v.z, v.w};
#pragma unroll
        for (int j = 0; j < 4; ++j) {
            float xb = xj[j];
#pragma unroll
            for (int c0 = 0; c0 < 40; c0 += 4) {
                float4 w = *(const float4*)&Ws[(k0 + j) * 40 + c0];
                acc[c0 + 0] = fmaf(xb, w.x, acc[c0 + 0]);
                acc[c0 + 1] = fmaf(xb, w.y, acc[c0 + 1]);
                acc[c0 + 2] = fmaf(xb, w.z, acc[c0 + 2]);
                acc[c0 + 3] = fmaf(xb, w.w, acc[c0 + 3]);
            }
        }
    }
    float s2 = 0.f, d2 = 0.f;
#pragma unroll
    for (int c = 0; c < 40; ++c) {
        s2 = fmaf(acc[c], att_s2[c], s2);
        d2 = fmaf(acc[c], att_d2[c], d2);
    }
    unsigned int p[20];
#pragma unroll
    for (int j = 0; j < 20; ++j) p[j] = pack_bf2(acc[2 * j], acc[2 * j + 1]);
#pragma unroll
    for (int j = 0; j < 5; ++j)
        *(uint4*)&h2b[(size_t)n * 20 + 4 * j] = make_uint4(p[4 * j], p[4 * j + 1], p[4 * j + 2], p[4 * j + 3]);
    a_src2[n] = s2;
    a_dst2[n] = d2;
}

// ---------------------------------------------------------------------------
// Layer-2 aggregation (H=1, C=40). Two nodes per wave (32 lanes each); lane
// u<20 owns channels 2u,2u+1 (one uint from h2b[node][20], 4 MB footprint).
// Per 32-edge chunk: lane u computes ev for edge u of its half (coalesced),
// staged with col in per-wave LDS strips. Writes final output (+bias2).
// ---------------------------------------------------------------------------
__global__ __launch_bounds__(256) void k_aggr2(const int* __restrict__ rowptr,
                                               const int* __restrict__ cnt,
                                               const int* __restrict__ col,
                                               const float* __restrict__ a_src,
                                               const float* __restrict__ a_dst,
                                               const unsigned int* __restrict__ h2b,
                                               const float* __restrict__ bias2,
                                               float* __restrict__ out, int N) {
    __shared__ float evs[4][2][32];
    __shared__ int   cls[4][2][32];
    int t = threadIdx.x;
    int w = t >> 6;
    int lane = t & 63;
    int half = lane >> 5;
    int u = lane & 31;
    int node = blockIdx.x * 8 + w * 2 + half;
    bool nv = (node < N);
    int nodec = nv ? node : (N - 1);
    int beg = rowptr[nodec];
    int deg = nv ? cnt[nodec] : 0;
    int degO = __shfl_xor(deg, 32);
    int degmax = (deg > degO) ? deg : degO;
    if (degmax <= 0) return;

    int ucl = (u < 20) ? u : 19;
    float ad = a_dst[nodec];
    float* myev = &evs[w][half][0];
    int*   mycl = &cls[w][half][0];

    float den = 0.f, a0 = 0.f, a1 = 0.f;
    int c = 0;
    while (c < degmax) {
        int slot = c + u;
        int slotc = (slot < deg) ? slot : (deg - 1);
        if (slotc < 0) slotc = 0;
        int su = col[beg + slotc];
        float ev = (slot < deg) ? __expf(lrelu(a_src[su] + ad)) : 0.f;
        myev[u] = ev;
        mycl[u] = su;

        int ccm = degmax - c; ccm = (ccm < 32) ? ccm : 32;
        int sP = mycl[0];
        unsigned int uP = h2b[sP * 20 + ucl];
        for (int i = 0; i < ccm; ++i) {
            int in = (i + 1 < ccm) ? (i + 1) : i;
            int sN = mycl[in];
            unsigned int uN = h2b[sN * 20 + ucl];
            float evv = myev[i];
            den += evv;
            a0 = fmaf(evv, bf_lo(uP), a0);
            a1 = fmaf(evv, bf_hi(uP), a1);
            uP = uN;
        }
        c += 32;
    }
    if (nv && u < 20) {
        float inv = 1.f / (den + 1e-16f);
        float2 b = *(const float2*)&bias2[2 * u];
        float2 o = make_float2(fmaf(a0, inv, b.x), fmaf(a1, inv, b.y));
        *(float2*)&out[(size_t)node * 40 + 2 * u] = o;
    }
}

// ---------------------------------------------------------------------------
extern "C" void kernel_launch(void* const* d_in, const int* in_sizes, int n_in,
                              void* d_out, int out_size, void* d_ws, size_t ws_size,
                              hipStream_t stream) {
    const float* x   = (const float*)d_in[0];
    const int*   ei  = (const int*)d_in[1];
    const float* W1  = (const float*)d_in[2];
    const float* as1 = (const float*)d_in[3];
    const float* ad1 = (const float*)d_in[4];
    const float* b1  = (const float*)d_in[5];
    const float* W2  = (const float*)d_in[6];
    const float* as2 = (const float*)d_in[7];
    const float* ad2 = (const float*)d_in[8];
    const float* b2  = (const float*)d_in[9];

    int N = in_sizes[0] / 128;
    int E = in_sizes[1] / 2;
    int EN = E + N;
    size_t Np = (size_t)((N + 3) & ~3);
    size_t ENp = ((size_t)EN + 3) & ~3;

    float* ws = (float*)d_ws;
    float* out1    = ws; ws += Np * 128;
    unsigned int* h1A = (unsigned int*)ws; ws += Np * 32;   // ch 0-63, bf16x2
    unsigned int* h1Bp = (unsigned int*)ws; ws += Np * 32;  // ch 64-127
    unsigned int* h2b = (unsigned int*)ws; ws += Np * 20;
    float* a_src1  = ws; ws += Np * 8;
    float* a_dst1  = ws; ws += Np * 8;
    float* a_src2v = ws; ws += Np;
    float* a_dst2v = ws; ws += Np;
    int* cnt    = (int*)ws; ws += Np;
    int* rowptr = (int*)ws; ws += Np;
    int* psum   = (int*)ws; ws += 256;
    int* col    = (int*)ws; ws += ENp;
    int* rank   = (int*)ws; ws += ENp;

    int nb = (N + 1023) / 1024;  // scan blocks (<=256)

    hipMemsetAsync(cnt, 0, (size_t)N * sizeof(int), stream);
    k_hist<<<(EN + 255) / 256, 256, 0, stream>>>(ei, E, N, cnt, rank);
    k_scan_part<<<nb, 256, 0, stream>>>(cnt, N, psum);
    k_scan_mid<<<1, 256, 0, stream>>>(psum, nb);
    k_scan_add<<<nb, 256, 0, stream>>>(cnt, N, psum, rowptr);
    k_scatter<<<(EN + 255) / 256, 256, 0, stream>>>(ei, E, N, rowptr, rank, col);

    k_gemm1<<<(N + 63) / 64, 256, 0, stream>>>(x, W1, as1, ad1, h1A, h1Bp, a_src1, a_dst1, N);
    int nag = (N + 7) / 8;
    k_aggr1<<<nag, 256, 0, stream>>>(rowptr, cnt, col, a_src1, a_dst1, h1A, b1, out1, N, 0);
    k_aggr1<<<nag, 256, 0, stream>>>(rowptr, cnt, col, a_src1, a_dst1, h1Bp, b1, out1, N, 1);
    k_gemm2<<<(N + 255) / 256, 256, 0, stream>>>(out1, W2, as2, ad2, h2b, a_src2v, a_dst2v, N);
    k_aggr2<<<nag, 256, 0, stream>>>(rowptr, cnt, col, a_src2v, a_dst2v, h2b, b2, (float*)d_out, N);
}

// Round 9
// 266.101 us; speedup vs baseline: 30.9164x; 1.0295x over previous
//
#include <hip/hip_runtime.h>
#include <hip/hip_bf16.h>
#include <math.h>

#define NEG_SLOPE 0.2f

typedef __bf16 bf16x8 __attribute__((ext_vector_type(8)));
typedef float f32x4 __attribute__((ext_vector_type(4)));

__device__ __forceinline__ float lrelu(float x) { return x > 0.f ? x : NEG_SLOPE * x; }

// pack two fp32 -> one uint holding 2 bf16 (RNE)
__device__ __forceinline__ unsigned int pack_bf2(float a, float b) {
    unsigned int ua = __float_as_uint(a);
    ua = (ua + 0x7fffu + ((ua >> 16) & 1u)) >> 16;
    unsigned int ub = __float_as_uint(b);
    ub = (ub + 0x7fffu + ((ub >> 16) & 1u)) & 0xffff0000u;
    return ua | ub;
}
__device__ __forceinline__ unsigned short f2bfu(float f) {
    unsigned int ua = __float_as_uint(f);
    return (unsigned short)((ua + 0x7fffu + ((ua >> 16) & 1u)) >> 16);
}
__device__ __forceinline__ float bf_lo(unsigned int u) { return __uint_as_float(u << 16); }
__device__ __forceinline__ float bf_hi(unsigned int u) { return __uint_as_float(u & 0xffff0000u); }

// ---------------------------------------------------------------------------
// histogram of dst (incl. self-loops); also emits rank[e] = arrival order
// ---------------------------------------------------------------------------
__global__ __launch_bounds__(256) void k_hist(const int* __restrict__ ei, int E, int N,
                                              int* __restrict__ cnt, int* __restrict__ rank) {
    int e = blockIdx.x * 256 + threadIdx.x;
    if (e >= E + N) return;
    int d = (e < E) ? ei[E + e] : (e - E);
    rank[e] = atomicAdd(&cnt[d], 1);
}

// ---------------------------------------------------------------------------
// 3-stage exclusive scan of cnt[N] -> rowptr[N]; chunk = 1024 per block
// ---------------------------------------------------------------------------
__global__ __launch_bounds__(256) void k_scan_part(const int* __restrict__ cnt, int N,
                                                   int* __restrict__ psum) {
    __shared__ int sh[256];
    int t = threadIdx.x;
    int base = blockIdx.x * 1024 + t * 4;
    int tl = 0;
#pragma unroll
    for (int j = 0; j < 4; ++j) tl += (base + j < N) ? cnt[base + j] : 0;
    sh[t] = tl; __syncthreads();
    for (int off = 128; off > 0; off >>= 1) {
        if (t < off) sh[t] += sh[t + off];
        __syncthreads();
    }
    if (t == 0) psum[blockIdx.x] = sh[0];
}

__global__ __launch_bounds__(256) void k_scan_mid(int* __restrict__ psum, int nb) {
    __shared__ int sh[256];
    int t = threadIdx.x;
    int v = (t < nb) ? psum[t] : 0;
    sh[t] = v; __syncthreads();
    for (int off = 1; off < 256; off <<= 1) {
        int a = (t >= off) ? sh[t - off] : 0;
        __syncthreads();
        sh[t] += a;
        __syncthreads();
    }
    psum[t] = sh[t] - v;  // exclusive
}

__global__ __launch_bounds__(256) void k_scan_add(const int* __restrict__ cnt, int N,
                                                  const int* __restrict__ psum,
                                                  int* __restrict__ rowptr) {
    __shared__ int sh[256];
    int t = threadIdx.x;
    int base = blockIdx.x * 1024 + t * 4;
    int c[4]; int tl = 0;
#pragma unroll
    for (int j = 0; j < 4; ++j) { c[j] = (base + j < N) ? cnt[base + j] : 0; tl += c[j]; }
    sh[t] = tl; __syncthreads();
    for (int off = 1; off < 256; off <<= 1) {
        int a = (t >= off) ? sh[t - off] : 0;
        __syncthreads();
        sh[t] += a;
        __syncthreads();
    }
    int run = psum[blockIdx.x] + (sh[t] - tl);
#pragma unroll
    for (int j = 0; j < 4; ++j) {
        if (base + j < N) { rowptr[base + j] = run; run += c[j]; }
    }
}

// ---------------------------------------------------------------------------
// scatter src into CSR by dst using precomputed rank (no atomics)
// ---------------------------------------------------------------------------
__global__ __launch_bounds__(256) void k_scatter(const int* __restrict__ ei, int E, int N,
                                                 const int* __restrict__ rowptr,
                                                 const int* __restrict__ rank,
                                                 int* __restrict__ col) {
    int e = blockIdx.x * 256 + threadIdx.x;
    if (e >= E + N) return;
    int s, d;
    if (e < E) { s = ei[e]; d = ei[E + e]; } else { s = d = e - E; }
    col[rowptr[d] + rank[e]] = s;
}

// ---------------------------------------------------------------------------
// W1 repack: fp32 [128,128] -> bf16 B-fragment layout for mfma 16x16x32.
// Fragment index idx = ((ct*4 + c)*4 + quad)*16 + n holds 8 bf16:
//   B[k = c*32 + quad*8 + j][n_col = ct*16 + n], j = 0..7.
// ---------------------------------------------------------------------------
__global__ __launch_bounds__(256) void k_wpack(const float* __restrict__ W,
                                               bf16x8* __restrict__ Wp) {
    int idx = blockIdx.x * 256 + threadIdx.x;   // 0..2047
    if (idx >= 2048) return;
    int n = idx & 15, quad = (idx >> 4) & 3, c = (idx >> 6) & 3, ct = idx >> 8;
    bf16x8 v;
#pragma unroll
    for (int j = 0; j < 8; ++j)
        v[j] = (__bf16)W[(c * 32 + quad * 8 + j) * 128 + ct * 16 + n];
    Wp[idx] = v;
}

// ---------------------------------------------------------------------------
// GEMM1 via MFMA: h1 = x @ W1 ([N,128]@[128,128]). One wave = 16 rows x 128
// cols; x split hi/lo bf16 (xh + xl) for near-fp32 accuracy; 8 col-tiles x
// 4 K-chunks x 2 = 64 mfma_f32_16x16x32_bf16 per wave. No LDS. Emits
// channel-split packed-bf16 h1A/h1B + fused fp32 a_src1/a_dst1 (quad-wise
// shfl_xor reduction in the epilogue).
// A layout: A[m=lane&15][k=quad*8+j]; D layout: row=quad*4+reg, col=lane&15.
// ---------------------------------------------------------------------------
__global__ __launch_bounds__(256) void k_gemm1(const float* __restrict__ x,
                                               const bf16x8* __restrict__ Wp,
                                               const float* __restrict__ att_s,
                                               const float* __restrict__ att_d,
                                               unsigned short* __restrict__ h1A,
                                               unsigned short* __restrict__ h1B,
                                               float* __restrict__ a_src,
                                               float* __restrict__ a_dst, int N) {
    int t = threadIdx.x;
    int w = t >> 6, lane = t & 63, quad = lane >> 4, n16 = lane & 15;
    int row0 = blockIdx.x * 64 + w * 16;
    int arow = row0 + n16; if (arow >= N) arow = N - 1;
    const float* px = x + (size_t)arow * 128;

    bf16x8 ah[4], al[4];
#pragma unroll
    for (int c = 0; c < 4; ++c) {
        float4 v0 = *(const float4*)&px[c * 32 + quad * 8];
        float4 v1 = *(const float4*)&px[c * 32 + quad * 8 + 4];
        float xf[8] = {v0.x, v0.y, v0.z, v0.w, v1.x, v1.y, v1.z, v1.w};
#pragma unroll
        for (int j = 0; j < 8; ++j) {
            __bf16 hi = (__bf16)xf[j];
            ah[c][j] = hi;
            al[c][j] = (__bf16)(xf[j] - (float)hi);
        }
    }

    f32x4 acc[8];
#pragma unroll
    for (int ct = 0; ct < 8; ++ct) acc[ct] = (f32x4){0.f, 0.f, 0.f, 0.f};

    const uint4* wp4 = (const uint4*)Wp;
#pragma unroll
    for (int ct = 0; ct < 8; ++ct) {
#pragma unroll
        for (int c = 0; c < 4; ++c) {
            union { uint4 u; bf16x8 b; } bu;
            bu.u = wp4[((ct * 4 + c) * 4 + quad) * 16 + n16];
            acc[ct] = __builtin_amdgcn_mfma_f32_16x16x32_bf16(ah[c], bu.b, acc[ct], 0, 0, 0);
            acc[ct] = __builtin_amdgcn_mfma_f32_16x16x32_bf16(al[c], bu.b, acc[ct], 0, 0, 0);
        }
    }

    float asv[8], adv[8];
#pragma unroll
    for (int ct = 0; ct < 8; ++ct) {
        asv[ct] = att_s[ct * 16 + n16];
        adv[ct] = att_d[ct * 16 + n16];
    }
    int nodeb = row0 + quad * 4;
#pragma unroll
    for (int ct = 0; ct < 8; ++ct) {
        unsigned short* hp = (ct < 4) ? h1A : h1B;
        int chl = (ct & 3) * 16 + n16;
#pragma unroll
        for (int reg = 0; reg < 4; ++reg) {
            int node = nodeb + reg;
            float hv = acc[ct][reg];
            float ps = hv * asv[ct];
            float pd = hv * adv[ct];
#pragma unroll
            for (int m = 1; m < 16; m <<= 1) {
                ps += __shfl_xor(ps, m);
                pd += __shfl_xor(pd, m);
            }
            if (node < N) {
                hp[(size_t)node * 64 + chl] = f2bfu(hv);
                if (n16 == 0) {
                    a_src[(size_t)node * 8 + ct] = ps;
                    a_dst[(size_t)node * 8 + ct] = pd;
                }
            }
        }
    }
}

// ---------------------------------------------------------------------------
// Layer-1 aggregation, channel-split pass p (p=0: ch 0-63 / heads 0-3;
// p=1: ch 64-127 / heads 4-7). Two nodes per wave (32 lanes each); lane u
// owns channels p*64+2u,2u+1. Per 32-edge chunk lane u computes 4 evs for
// edge u (coalesced a_src float4 gather) into per-wave LDS strips
// (wave-synchronous). Writes out1 columns [p*64, p*64+64).
// ---------------------------------------------------------------------------
__global__ __launch_bounds__(256) void k_aggr1(const int* __restrict__ rowptr,
                                               const int* __restrict__ cnt,
                                               const int* __restrict__ col,
                                               const float* __restrict__ a_src,
                                               const float* __restrict__ a_dst,
                                               const unsigned int* __restrict__ hp,
                                               const float* __restrict__ bias1,
                                               float* __restrict__ out1, int N, int p) {
    __shared__ float evs[4][2][128];   // [wave][half][edge*4+head]
    __shared__ int   cls[4][2][32];    // [wave][half][edge]
    int t = threadIdx.x;
    int w = t >> 6;
    int lane = t & 63;
    int half = lane >> 5;
    int u = lane & 31;
    int node = blockIdx.x * 8 + w * 2 + half;
    bool nv = (node < N);
    int nodec = nv ? node : (N - 1);
    int beg = rowptr[nodec];
    int deg = nv ? cnt[nodec] : 0;
    int degO = __shfl_xor(deg, 32);
    int degmax = (deg > degO) ? deg : degO;
    if (degmax <= 0) return;   // uniform across wave

    int hh = u >> 3;                           // phase-local head 0..3
    float4 ad4 = *(const float4*)&a_dst[(size_t)nodec * 8 + p * 4];

    float* myev = &evs[w][half][0];
    int*   mycl = &cls[w][half][0];

    float den = 0.f, n0 = 0.f, n1 = 0.f;
    int c = 0;
    while (c < degmax) {
        int slot = c + u;
        int slotc = (slot < deg) ? slot : (deg - 1);
        if (slotc < 0) slotc = 0;
        int su = col[beg + slotc];
        float4 as4 = *(const float4*)&a_src[(size_t)su * 8 + p * 4];
        bool valid = (slot < deg);
        float e0 = valid ? __expf(lrelu(as4.x + ad4.x)) : 0.f;
        float e1 = valid ? __expf(lrelu(as4.y + ad4.y)) : 0.f;
        float e2 = valid ? __expf(lrelu(as4.z + ad4.z)) : 0.f;
        float e3 = valid ? __expf(lrelu(as4.w + ad4.w)) : 0.f;
        *(float4*)&myev[u * 4] = make_float4(e0, e1, e2, e3);
        mycl[u] = su;
        // wave-synchronous LDS: single-wave producer/consumer, no barrier

        int ccm = degmax - c; ccm = (ccm < 32) ? ccm : 32;
        int sP = mycl[0];
        unsigned int uP = hp[sP * 32 + u];
        for (int i = 0; i < ccm; ++i) {
            int in = (i + 1 < ccm) ? (i + 1) : i;
            int sN = mycl[in];
            unsigned int uN = hp[sN * 32 + u];
            float ev = myev[i * 4 + hh];
            den += ev;
            n0 = fmaf(ev, bf_lo(uP), n0);
            n1 = fmaf(ev, bf_hi(uP), n1);
            uP = uN;
        }
        c += 32;
    }
    if (nv) {
        float inv = 1.f / (den + 1e-16f);
        int ch = p * 64 + 2 * u;
        float2 b = *(const float2*)&bias1[ch];
        float2 o = make_float2(fmaf(n0, inv, b.x), fmaf(n1, inv, b.y));
        *(float2*)&out1[(size_t)node * 128 + ch] = o;
    }
}

// ---------------------------------------------------------------------------
// GEMM2: h2 = out1 @ W2 ([N,128]@[128,40]); emits h2 as packed bf16 rows
// (80 B/row) + fused fp32 a_src2/a_dst2.
// ---------------------------------------------------------------------------
__global__ __launch_bounds__(256) void k_gemm2(const float* __restrict__ out1,
                                               const float* __restrict__ W2,
                                               const float* __restrict__ att_s2,
                                               const float* __restrict__ att_d2,
                                               unsigned int* __restrict__ h2b,  // [N][20] uints
                                               float* __restrict__ a_src2,
                                               float* __restrict__ a_dst2, int N) {
    __shared__ float Ws[128 * 40];
    int t = threadIdx.x;
    for (int i = t * 4; i < 128 * 40; i += 256 * 4)
        *(float4*)&Ws[i] = *(const float4*)&W2[i];
    __syncthreads();
    int n = blockIdx.x * 256 + t;
    if (n >= N) return;

    float acc[40];
#pragma unroll
    for (int c = 0; c < 40; ++c) acc[c] = 0.f;

    for (int k0 = 0; k0 < 128; k0 += 4) {
        float4 v = *(const float4*)&out1[(size_t)n * 128 + k0];
        float xj[4] = {v.x, v.y, v.z, v.w};
#pragma unroll
        for (int j = 0; j < 4; ++j) {
            float xb = xj[j];
#pragma unroll
            for (int c0 = 0; c0 < 40; c0 += 4) {
                float4 wv = *(const float4*)&Ws[(k0 + j) * 40 + c0];
                acc[c0 + 0] = fmaf(xb, wv.x, acc[c0 + 0]);
                acc[c0 + 1] = fmaf(xb, wv.y, acc[c0 + 1]);
                acc[c0 + 2] = fmaf(xb, wv.z, acc[c0 + 2]);
                acc[c0 + 3] = fmaf(xb, wv.w, acc[c0 + 3]);
            }
        }
    }
    float s2 = 0.f, d2 = 0.f;
#pragma unroll
    for (int c = 0; c < 40; ++c) {
        s2 = fmaf(acc[c], att_s2[c], s2);
        d2 = fmaf(acc[c], att_d2[c], d2);
    }
    unsigned int p[20];
#pragma unroll
    for (int j = 0; j < 20; ++j) p[j] = pack_bf2(acc[2 * j], acc[2 * j + 1]);
#pragma unroll
    for (int j = 0; j < 5; ++j)
        *(uint4*)&h2b[(size_t)n * 20 + 4 * j] = make_uint4(p[4 * j], p[4 * j + 1], p[4 * j + 2], p[4 * j + 3]);
    a_src2[n] = s2;
    a_dst2[n] = d2;
}

// ---------------------------------------------------------------------------
// Layer-2 aggregation (H=1, C=40). Two nodes per wave (32 lanes each); lane
// u<20 owns channels 2u,2u+1 (4 MB h2b footprint). Per 32-edge chunk lane u
// computes ev for edge u (coalesced), staged with col in per-wave LDS strips.
// Writes final output (+bias2).
// ---------------------------------------------------------------------------
__global__ __launch_bounds__(256) void k_aggr2(const int* __restrict__ rowptr,
                                               const int* __restrict__ cnt,
                                               const int* __restrict__ col,
                                               const float* __restrict__ a_src,
                                               const float* __restrict__ a_dst,
                                               const unsigned int* __restrict__ h2b,
                                               const float* __restrict__ bias2,
                                               float* __restrict__ out, int N) {
    __shared__ float evs[4][2][32];
    __shared__ int   cls[4][2][32];
    int t = threadIdx.x;
    int w = t >> 6;
    int lane = t & 63;
    int half = lane >> 5;
    int u = lane & 31;
    int node = blockIdx.x * 8 + w * 2 + half;
    bool nv = (node < N);
    int nodec = nv ? node : (N - 1);
    int beg = rowptr[nodec];
    int deg = nv ? cnt[nodec] : 0;
    int degO = __shfl_xor(deg, 32);
    int degmax = (deg > degO) ? deg : degO;
    if (degmax <= 0) return;

    int ucl = (u < 20) ? u : 19;
    float ad = a_dst[nodec];
    float* myev = &evs[w][half][0];
    int*   mycl = &cls[w][half][0];

    float den = 0.f, a0 = 0.f, a1 = 0.f;
    int c = 0;
    while (c < degmax) {
        int slot = c + u;
        int slotc = (slot < deg) ? slot : (deg - 1);
        if (slotc < 0) slotc = 0;
        int su = col[beg + slotc];
        float ev = (slot < deg) ? __expf(lrelu(a_src[su] + ad)) : 0.f;
        myev[u] = ev;
        mycl[u] = su;

        int ccm = degmax - c; ccm = (ccm < 32) ? ccm : 32;
        int sP = mycl[0];
        unsigned int uP = h2b[sP * 20 + ucl];
        for (int i = 0; i < ccm; ++i) {
            int in = (i + 1 < ccm) ? (i + 1) : i;
            int sN = mycl[in];
            unsigned int uN = h2b[sN * 20 + ucl];
            float evv = myev[i];
            den += evv;
            a0 = fmaf(evv, bf_lo(uP), a0);
            a1 = fmaf(evv, bf_hi(uP), a1);
            uP = uN;
        }
        c += 32;
    }
    if (nv && u < 20) {
        float inv = 1.f / (den + 1e-16f);
        float2 b = *(const float2*)&bias2[2 * u];
        float2 o = make_float2(fmaf(a0, inv, b.x), fmaf(a1, inv, b.y));
        *(float2*)&out[(size_t)node * 40 + 2 * u] = o;
    }
}

// ---------------------------------------------------------------------------
extern "C" void kernel_launch(void* const* d_in, const int* in_sizes, int n_in,
                              void* d_out, int out_size, void* d_ws, size_t ws_size,
                              hipStream_t stream) {
    const float* x   = (const float*)d_in[0];
    const int*   ei  = (const int*)d_in[1];
    const float* W1  = (const float*)d_in[2];
    const float* as1 = (const float*)d_in[3];
    const float* ad1 = (const float*)d_in[4];
    const float* b1  = (const float*)d_in[5];
    const float* W2  = (const float*)d_in[6];
    const float* as2 = (const float*)d_in[7];
    const float* ad2 = (const float*)d_in[8];
    const float* b2  = (const float*)d_in[9];

    int N = in_sizes[0] / 128;
    int E = in_sizes[1] / 2;
    int EN = E + N;
    size_t Np = (size_t)((N + 3) & ~3);
    size_t ENp = ((size_t)EN + 3) & ~3;

    float* ws = (float*)d_ws;
    float* out1    = ws; ws += Np * 128;
    unsigned int* h1A = (unsigned int*)ws; ws += Np * 32;   // ch 0-63, bf16x2
    unsigned int* h1Bp = (unsigned int*)ws; ws += Np * 32;  // ch 64-127
    unsigned int* h2b = (unsigned int*)ws; ws += Np * 20;
    float* a_src1  = ws; ws += Np * 8;
    float* a_dst1  = ws; ws += Np * 8;
    float* a_src2v = ws; ws += Np;
    float* a_dst2v = ws; ws += Np;
    bf16x8* Wp = (bf16x8*)ws; ws += 2048 * 4;               // 32 KB repacked W1
    int* cnt    = (int*)ws; ws += Np;
    int* rowptr = (int*)ws; ws += Np;
    int* psum   = (int*)ws; ws += 256;
    int* col    = (int*)ws; ws += ENp;
    int* rank   = (int*)ws; ws += ENp;

    int nb = (N + 1023) / 1024;  // scan blocks (<=256)

    hipMemsetAsync(cnt, 0, (size_t)N * sizeof(int), stream);
    k_wpack<<<8, 256, 0, stream>>>(W1, Wp);
    k_hist<<<(EN + 255) / 256, 256, 0, stream>>>(ei, E, N, cnt, rank);
    k_scan_part<<<nb, 256, 0, stream>>>(cnt, N, psum);
    k_scan_mid<<<1, 256, 0, stream>>>(psum, nb);
    k_scan_add<<<nb, 256, 0, stream>>>(cnt, N, psum, rowptr);
    k_scatter<<<(EN + 255) / 256, 256, 0, stream>>>(ei, E, N, rowptr, rank, col);

    k_gemm1<<<(N + 63) / 64, 256, 0, stream>>>(x, Wp, as1, ad1,
                                               (unsigned short*)h1A, (unsigned short*)h1Bp,
                                               a_src1, a_dst1, N);
    int nag = (N + 7) / 8;
    k_aggr1<<<nag, 256, 0, stream>>>(rowptr, cnt, col, a_src1, a_dst1, h1A, b1, out1, N, 0);
    k_aggr1<<<nag, 256, 0, stream>>>(rowptr, cnt, col, a_src1, a_dst1, h1Bp, b1, out1, N, 1);
    k_gemm2<<<(N + 255) / 256, 256, 0, stream>>>(out1, W2, as2, ad2, h2b, a_src2v, a_dst2v, N);
    k_aggr2<<<nag, 256, 0, stream>>>(rowptr, cnt, col, a_src2v, a_dst2v, h2b, b2, (float*)d_out, N);
}

// Round 10
// 249.443 us; speedup vs baseline: 32.9810x; 1.0668x over previous
//
#include <hip/hip_runtime.h>
#include <hip/hip_bf16.h>
#include <math.h>

#define NEG_SLOPE 0.2f

typedef __bf16 bf16x8 __attribute__((ext_vector_type(8)));
typedef float f32x4 __attribute__((ext_vector_type(4)));

__device__ __forceinline__ float lrelu(float x) { return x > 0.f ? x : NEG_SLOPE * x; }

__device__ __forceinline__ unsigned short f2bfu(float f) {
    unsigned int ua = __float_as_uint(f);
    return (unsigned short)((ua + 0x7fffu + ((ua >> 16) & 1u)) >> 16);
}
__device__ __forceinline__ float bfu2f(unsigned short u) {
    return __uint_as_float(((unsigned int)u) << 16);
}
__device__ __forceinline__ float bf_lo(unsigned int u) { return __uint_as_float(u << 16); }
__device__ __forceinline__ float bf_hi(unsigned int u) { return __uint_as_float(u & 0xffff0000u); }

// ---------------------------------------------------------------------------
// histogram of dst (incl. self-loops); also emits rank[e] = arrival order
// ---------------------------------------------------------------------------
__global__ __launch_bounds__(256) void k_hist(const int* __restrict__ ei, int E, int N,
                                              int* __restrict__ cnt, int* __restrict__ rank) {
    int e = blockIdx.x * 256 + threadIdx.x;
    if (e >= E + N) return;
    int d = (e < E) ? ei[E + e] : (e - E);
    rank[e] = atomicAdd(&cnt[d], 1);
}

// ---------------------------------------------------------------------------
// 3-stage exclusive scan of cnt[N] -> rowptr[N]; chunk = 1024 per block
// ---------------------------------------------------------------------------
__global__ __launch_bounds__(256) void k_scan_part(const int* __restrict__ cnt, int N,
                                                   int* __restrict__ psum) {
    __shared__ int sh[256];
    int t = threadIdx.x;
    int base = blockIdx.x * 1024 + t * 4;
    int tl = 0;
#pragma unroll
    for (int j = 0; j < 4; ++j) tl += (base + j < N) ? cnt[base + j] : 0;
    sh[t] = tl; __syncthreads();
    for (int off = 128; off > 0; off >>= 1) {
        if (t < off) sh[t] += sh[t + off];
        __syncthreads();
    }
    if (t == 0) psum[blockIdx.x] = sh[0];
}

__global__ __launch_bounds__(256) void k_scan_mid(int* __restrict__ psum, int nb) {
    __shared__ int sh[256];
    int t = threadIdx.x;
    int v = (t < nb) ? psum[t] : 0;
    sh[t] = v; __syncthreads();
    for (int off = 1; off < 256; off <<= 1) {
        int a = (t >= off) ? sh[t - off] : 0;
        __syncthreads();
        sh[t] += a;
        __syncthreads();
    }
    psum[t] = sh[t] - v;  // exclusive
}

__global__ __launch_bounds__(256) void k_scan_add(const int* __restrict__ cnt, int N,
                                                  const int* __restrict__ psum,
                                                  int* __restrict__ rowptr) {
    __shared__ int sh[256];
    int t = threadIdx.x;
    int base = blockIdx.x * 1024 + t * 4;
    int c[4]; int tl = 0;
#pragma unroll
    for (int j = 0; j < 4; ++j) { c[j] = (base + j < N) ? cnt[base + j] : 0; tl += c[j]; }
    sh[t] = tl; __syncthreads();
    for (int off = 1; off < 256; off <<= 1) {
        int a = (t >= off) ? sh[t - off] : 0;
        __syncthreads();
        sh[t] += a;
        __syncthreads();
    }
    int run = psum[blockIdx.x] + (sh[t] - tl);
#pragma unroll
    for (int j = 0; j < 4; ++j) {
        if (base + j < N) { rowptr[base + j] = run; run += c[j]; }
    }
}

// ---------------------------------------------------------------------------
// scatter src into CSR by dst using precomputed rank (no atomics)
// ---------------------------------------------------------------------------
__global__ __launch_bounds__(256) void k_scatter(const int* __restrict__ ei, int E, int N,
                                                 const int* __restrict__ rowptr,
                                                 const int* __restrict__ rank,
                                                 int* __restrict__ col) {
    int e = blockIdx.x * 256 + threadIdx.x;
    if (e >= E + N) return;
    int s, d;
    if (e < E) { s = ei[e]; d = ei[E + e]; } else { s = d = e - E; }
    col[rowptr[d] + rank[e]] = s;
}

// ---------------------------------------------------------------------------
// W1 repack: fp32 [128,128] -> bf16 B-fragment layout for mfma 16x16x32.
// idx = ((ct*4 + c)*4 + quad)*16 + n : B[k=c*32+quad*8+j][col=ct*16+n], j=0..7
// ---------------------------------------------------------------------------
__global__ __launch_bounds__(256) void k_wpack(const float* __restrict__ W,
                                               bf16x8* __restrict__ Wp) {
    int idx = blockIdx.x * 256 + threadIdx.x;   // 0..2047
    if (idx >= 2048) return;
    int n = idx & 15, quad = (idx >> 4) & 3, c = (idx >> 6) & 3, ct = idx >> 8;
    bf16x8 v;
#pragma unroll
    for (int j = 0; j < 8; ++j)
        v[j] = (__bf16)W[(c * 32 + quad * 8 + j) * 128 + ct * 16 + n];
    Wp[idx] = v;
}

// ---------------------------------------------------------------------------
// W2 repack: fp32 [128,40] -> bf16 B-fragments, cols padded to 48 (3 tiles).
// idx = ((ct*4 + c)*4 + quad)*16 + n, ct=0..2 (768 frags, 12 KB).
// ---------------------------------------------------------------------------
__global__ __launch_bounds__(256) void k_wpack2(const float* __restrict__ W2,
                                                bf16x8* __restrict__ W2p) {
    int idx = blockIdx.x * 256 + threadIdx.x;   // 0..767
    if (idx >= 768) return;
    int n = idx & 15, quad = (idx >> 4) & 3, c = (idx >> 6) & 3, ct = idx >> 8;
    int colc = ct * 16 + n;
    bf16x8 v;
#pragma unroll
    for (int j = 0; j < 8; ++j)
        v[j] = (colc < 40) ? (__bf16)W2[(c * 32 + quad * 8 + j) * 40 + colc] : (__bf16)0.f;
    W2p[idx] = v;
}

// ---------------------------------------------------------------------------
// GEMM1 via MFMA: h1 = x @ W1. One wave = 16 rows x 128 cols; x split hi/lo
// bf16; 8 ct x 4 kc x 2 = 64 mfma. No LDS. Emits channel-split packed-bf16
// h1A/h1B + fused fp32 a_src1/a_dst1.
// ---------------------------------------------------------------------------
__global__ __launch_bounds__(256) void k_gemm1(const float* __restrict__ x,
                                               const bf16x8* __restrict__ Wp,
                                               const float* __restrict__ att_s,
                                               const float* __restrict__ att_d,
                                               unsigned short* __restrict__ h1A,
                                               unsigned short* __restrict__ h1B,
                                               float* __restrict__ a_src,
                                               float* __restrict__ a_dst, int N) {
    int t = threadIdx.x;
    int w = t >> 6, lane = t & 63, quad = lane >> 4, n16 = lane & 15;
    int row0 = blockIdx.x * 64 + w * 16;
    int arow = row0 + n16; if (arow >= N) arow = N - 1;
    const float* px = x + (size_t)arow * 128;

    bf16x8 ah[4], al[4];
#pragma unroll
    for (int c = 0; c < 4; ++c) {
        float4 v0 = *(const float4*)&px[c * 32 + quad * 8];
        float4 v1 = *(const float4*)&px[c * 32 + quad * 8 + 4];
        float xf[8] = {v0.x, v0.y, v0.z, v0.w, v1.x, v1.y, v1.z, v1.w};
#pragma unroll
        for (int j = 0; j < 8; ++j) {
            __bf16 hi = (__bf16)xf[j];
            ah[c][j] = hi;
            al[c][j] = (__bf16)(xf[j] - (float)hi);
        }
    }

    f32x4 acc[8];
#pragma unroll
    for (int ct = 0; ct < 8; ++ct) acc[ct] = (f32x4){0.f, 0.f, 0.f, 0.f};

    const uint4* wp4 = (const uint4*)Wp;
#pragma unroll
    for (int ct = 0; ct < 8; ++ct) {
#pragma unroll
        for (int c = 0; c < 4; ++c) {
            union { uint4 u; bf16x8 b; } bu;
            bu.u = wp4[((ct * 4 + c) * 4 + quad) * 16 + n16];
            acc[ct] = __builtin_amdgcn_mfma_f32_16x16x32_bf16(ah[c], bu.b, acc[ct], 0, 0, 0);
            acc[ct] = __builtin_amdgcn_mfma_f32_16x16x32_bf16(al[c], bu.b, acc[ct], 0, 0, 0);
        }
    }

    float asv[8], adv[8];
#pragma unroll
    for (int ct = 0; ct < 8; ++ct) {
        asv[ct] = att_s[ct * 16 + n16];
        adv[ct] = att_d[ct * 16 + n16];
    }
    int nodeb = row0 + quad * 4;
#pragma unroll
    for (int ct = 0; ct < 8; ++ct) {
        unsigned short* hp = (ct < 4) ? h1A : h1B;
        int chl = (ct & 3) * 16 + n16;
#pragma unroll
        for (int reg = 0; reg < 4; ++reg) {
            int node = nodeb + reg;
            float hv = acc[ct][reg];
            float ps = hv * asv[ct];
            float pd = hv * adv[ct];
#pragma unroll
            for (int m = 1; m < 16; m <<= 1) {
                ps += __shfl_xor(ps, m);
                pd += __shfl_xor(pd, m);
            }
            if (node < N) {
                hp[(size_t)node * 64 + chl] = f2bfu(hv);
                if (n16 == 0) {
                    a_src[(size_t)node * 8 + ct] = ps;
                    a_dst[(size_t)node * 8 + ct] = pd;
                }
            }
        }
    }
}

// ---------------------------------------------------------------------------
// Layer-1 aggregation, channel-split pass p. Two nodes per wave (32 lanes);
// lane u owns channels p*64+2u,2u+1. Emits out1 as hi/lo packed-bf16 pairs
// (out1h/out1l, uint per channel-pair) for the MFMA GEMM2.
// ---------------------------------------------------------------------------
__global__ __launch_bounds__(256) void k_aggr1(const int* __restrict__ rowptr,
                                               const int* __restrict__ cnt,
                                               const int* __restrict__ col,
                                               const float* __restrict__ a_src,
                                               const float* __restrict__ a_dst,
                                               const unsigned int* __restrict__ hp,
                                               const float* __restrict__ bias1,
                                               unsigned int* __restrict__ out1h,
                                               unsigned int* __restrict__ out1l, int N, int p) {
    __shared__ float evs[4][2][128];   // [wave][half][edge*4+head]
    __shared__ int   cls[4][2][32];    // [wave][half][edge]
    int t = threadIdx.x;
    int w = t >> 6;
    int lane = t & 63;
    int half = lane >> 5;
    int u = lane & 31;
    int node = blockIdx.x * 8 + w * 2 + half;
    bool nv = (node < N);
    int nodec = nv ? node : (N - 1);
    int beg = rowptr[nodec];
    int deg = nv ? cnt[nodec] : 0;
    int degO = __shfl_xor(deg, 32);
    int degmax = (deg > degO) ? deg : degO;
    if (degmax <= 0) return;   // uniform across wave

    int hh = u >> 3;                           // phase-local head 0..3
    float4 ad4 = *(const float4*)&a_dst[(size_t)nodec * 8 + p * 4];

    float* myev = &evs[w][half][0];
    int*   mycl = &cls[w][half][0];

    float den = 0.f, n0 = 0.f, n1 = 0.f;
    int c = 0;
    while (c < degmax) {
        int slot = c + u;
        int slotc = (slot < deg) ? slot : (deg - 1);
        if (slotc < 0) slotc = 0;
        int su = col[beg + slotc];
        float4 as4 = *(const float4*)&a_src[(size_t)su * 8 + p * 4];
        bool valid = (slot < deg);
        float e0 = valid ? __expf(lrelu(as4.x + ad4.x)) : 0.f;
        float e1 = valid ? __expf(lrelu(as4.y + ad4.y)) : 0.f;
        float e2 = valid ? __expf(lrelu(as4.z + ad4.z)) : 0.f;
        float e3 = valid ? __expf(lrelu(as4.w + ad4.w)) : 0.f;
        *(float4*)&myev[u * 4] = make_float4(e0, e1, e2, e3);
        mycl[u] = su;
        // wave-synchronous LDS: single-wave producer/consumer, no barrier

        int ccm = degmax - c; ccm = (ccm < 32) ? ccm : 32;
        int sP = mycl[0];
        unsigned int uP = hp[sP * 32 + u];
        for (int i = 0; i < ccm; ++i) {
            int in = (i + 1 < ccm) ? (i + 1) : i;
            int sN = mycl[in];
            unsigned int uN = hp[sN * 32 + u];
            float ev = myev[i * 4 + hh];
            den += ev;
            n0 = fmaf(ev, bf_lo(uP), n0);
            n1 = fmaf(ev, bf_hi(uP), n1);
            uP = uN;
        }
        c += 32;
    }
    if (nv) {
        float inv = 1.f / (den + 1e-16f);
        int ch = p * 64 + 2 * u;
        float2 b = *(const float2*)&bias1[ch];
        float o0 = fmaf(n0, inv, b.x), o1 = fmaf(n1, inv, b.y);
        unsigned short h0 = f2bfu(o0), h1 = f2bfu(o1);
        float l0 = o0 - bfu2f(h0), l1 = o1 - bfu2f(h1);
        size_t idx = (size_t)node * 64 + p * 32 + u;
        out1h[idx] = (unsigned int)h0 | ((unsigned int)h1 << 16);
        out1l[idx] = (unsigned int)f2bfu(l0) | ((unsigned int)f2bfu(l1) << 16);
    }
}

// ---------------------------------------------------------------------------
// GEMM2 via MFMA: h2 = out1 @ W2 ([N,128]@[128,40->48]). One wave = 16 rows
// x 48 cols; out1 consumed as hi/lo bf16 (near-fp32); 3 ct x 4 kc x 2 = 24
// mfma. No LDS. Emits bf16 h2 rows (ushort[40]) + fused fp32 a_src2/a_dst2.
// ---------------------------------------------------------------------------
__global__ __launch_bounds__(256) void k_gemm2(const unsigned int* __restrict__ out1h,
                                               const unsigned int* __restrict__ out1l,
                                               const bf16x8* __restrict__ W2p,
                                               const float* __restrict__ att_s2,
                                               const float* __restrict__ att_d2,
                                               unsigned short* __restrict__ h2s,
                                               float* __restrict__ a_src2,
                                               float* __restrict__ a_dst2, int N) {
    int t = threadIdx.x;
    int w = t >> 6, lane = t & 63, quad = lane >> 4, n16 = lane & 15;
    int row0 = blockIdx.x * 64 + w * 16;
    int arow = row0 + n16; if (arow >= N) arow = N - 1;

    bf16x8 ah[4], al[4];
#pragma unroll
    for (int c = 0; c < 4; ++c) {
        // 4 uints = 8 bf16 (K-consecutive pairs) starting at k = c*32+quad*8
        size_t base = (size_t)arow * 64 + (c * 32 + quad * 8) / 2;
        union { uint4 u; bf16x8 b; } hu, lu;
        hu.u = *(const uint4*)&out1h[base];
        lu.u = *(const uint4*)&out1l[base];
        ah[c] = hu.b;
        al[c] = lu.b;
    }

    f32x4 acc[3];
#pragma unroll
    for (int ct = 0; ct < 3; ++ct) acc[ct] = (f32x4){0.f, 0.f, 0.f, 0.f};

    const uint4* wp4 = (const uint4*)W2p;
#pragma unroll
    for (int ct = 0; ct < 3; ++ct) {
#pragma unroll
        for (int c = 0; c < 4; ++c) {
            union { uint4 u; bf16x8 b; } bu;
            bu.u = wp4[((ct * 4 + c) * 4 + quad) * 16 + n16];
            acc[ct] = __builtin_amdgcn_mfma_f32_16x16x32_bf16(ah[c], bu.b, acc[ct], 0, 0, 0);
            acc[ct] = __builtin_amdgcn_mfma_f32_16x16x32_bf16(al[c], bu.b, acc[ct], 0, 0, 0);
        }
    }

    float asv[3], adv[3];
#pragma unroll
    for (int ct = 0; ct < 3; ++ct) {
        int ch = ct * 16 + n16;
        asv[ct] = (ch < 40) ? att_s2[ch] : 0.f;
        adv[ct] = (ch < 40) ? att_d2[ch] : 0.f;
    }
    int nodeb = row0 + quad * 4;
#pragma unroll
    for (int reg = 0; reg < 4; ++reg) {
        int node = nodeb + reg;
        float ps = 0.f, pd = 0.f;
#pragma unroll
        for (int ct = 0; ct < 3; ++ct) {
            float hv = acc[ct][reg];
            ps = fmaf(hv, asv[ct], ps);
            pd = fmaf(hv, adv[ct], pd);
            int ch = ct * 16 + n16;
            if (node < N && ch < 40) h2s[(size_t)node * 40 + ch] = f2bfu(hv);
        }
#pragma unroll
        for (int m = 1; m < 16; m <<= 1) {
            ps += __shfl_xor(ps, m);
            pd += __shfl_xor(pd, m);
        }
        if (node < N && n16 == 0) {
            a_src2[node] = ps;
            a_dst2[node] = pd;
        }
    }
}

// ---------------------------------------------------------------------------
// Layer-2 aggregation (H=1, C=40). Two nodes per wave (32 lanes each); lane
// u<20 owns channels 2u,2u+1 (4 MB h2 footprint). Writes final output
// (+bias2) directly.
// ---------------------------------------------------------------------------
__global__ __launch_bounds__(256) void k_aggr2(const int* __restrict__ rowptr,
                                               const int* __restrict__ cnt,
                                               const int* __restrict__ col,
                                               const float* __restrict__ a_src,
                                               const float* __restrict__ a_dst,
                                               const unsigned int* __restrict__ h2b,
                                               const float* __restrict__ bias2,
                                               float* __restrict__ out, int N) {
    __shared__ float evs[4][2][32];
    __shared__ int   cls[4][2][32];
    int t = threadIdx.x;
    int w = t >> 6;
    int lane = t & 63;
    int half = lane >> 5;
    int u = lane & 31;
    int node = blockIdx.x * 8 + w * 2 + half;
    bool nv = (node < N);
    int nodec = nv ? node : (N - 1);
    int beg = rowptr[nodec];
    int deg = nv ? cnt[nodec] : 0;
    int degO = __shfl_xor(deg, 32);
    int degmax = (deg > degO) ? deg : degO;
    if (degmax <= 0) return;

    int ucl = (u < 20) ? u : 19;
    float ad = a_dst[nodec];
    float* myev = &evs[w][half][0];
    int*   mycl = &cls[w][half][0];

    float den = 0.f, a0 = 0.f, a1 = 0.f;
    int c = 0;
    while (c < degmax) {
        int slot = c + u;
        int slotc = (slot < deg) ? slot : (deg - 1);
        if (slotc < 0) slotc = 0;
        int su = col[beg + slotc];
        float ev = (slot < deg) ? __expf(lrelu(a_src[su] + ad)) : 0.f;
        myev[u] = ev;
        mycl[u] = su;

        int ccm = degmax - c; ccm = (ccm < 32) ? ccm : 32;
        int sP = mycl[0];
        unsigned int uP = h2b[sP * 20 + ucl];
        for (int i = 0; i < ccm; ++i) {
            int in = (i + 1 < ccm) ? (i + 1) : i;
            int sN = mycl[in];
            unsigned int uN = h2b[sN * 20 + ucl];
            float evv = myev[i];
            den += evv;
            a0 = fmaf(evv, bf_lo(uP), a0);
            a1 = fmaf(evv, bf_hi(uP), a1);
            uP = uN;
        }
        c += 32;
    }
    if (nv && u < 20) {
        float inv = 1.f / (den + 1e-16f);
        float2 b = *(const float2*)&bias2[2 * u];
        float2 o = make_float2(fmaf(a0, inv, b.x), fmaf(a1, inv, b.y));
        *(float2*)&out[(size_t)node * 40 + 2 * u] = o;
    }
}

// ---------------------------------------------------------------------------
extern "C" void kernel_launch(void* const* d_in, const int* in_sizes, int n_in,
                              void* d_out, int out_size, void* d_ws, size_t ws_size,
                              hipStream_t stream) {
    const float* x   = (const float*)d_in[0];
    const int*   ei  = (const int*)d_in[1];
    const float* W1  = (const float*)d_in[2];
    const float* as1 = (const float*)d_in[3];
    const float* ad1 = (const float*)d_in[4];
    const float* b1  = (const float*)d_in[5];
    const float* W2  = (const float*)d_in[6];
    const float* as2 = (const float*)d_in[7];
    const float* ad2 = (const float*)d_in[8];
    const float* b2  = (const float*)d_in[9];

    int N = in_sizes[0] / 128;
    int E = in_sizes[1] / 2;
    int EN = E + N;
    size_t Np = (size_t)((N + 3) & ~3);
    size_t ENp = ((size_t)EN + 3) & ~3;

    float* ws = (float*)d_ws;
    unsigned int* out1h = (unsigned int*)ws; ws += Np * 64;  // hi bf16 pairs
    unsigned int* out1l = (unsigned int*)ws; ws += Np * 64;  // lo bf16 pairs
    unsigned int* h1A = (unsigned int*)ws; ws += Np * 32;    // ch 0-63, bf16x2
    unsigned int* h1Bp = (unsigned int*)ws; ws += Np * 32;   // ch 64-127
    unsigned int* h2b = (unsigned int*)ws; ws += Np * 20;
    float* a_src1  = ws; ws += Np * 8;
    float* a_dst1  = ws; ws += Np * 8;
    float* a_src2v = ws; ws += Np;
    float* a_dst2v = ws; ws += Np;
    bf16x8* Wp  = (bf16x8*)ws; ws += 2048 * 4;               // 32 KB repacked W1
    bf16x8* W2p = (bf16x8*)ws; ws += 768 * 4;                // 12 KB repacked W2
    int* cnt    = (int*)ws; ws += Np;
    int* rowptr = (int*)ws; ws += Np;
    int* psum   = (int*)ws; ws += 256;
    int* col    = (int*)ws; ws += ENp;
    int* rank   = (int*)ws; ws += ENp;

    int nb = (N + 1023) / 1024;  // scan blocks (<=256)

    hipMemsetAsync(cnt, 0, (size_t)N * sizeof(int), stream);
    k_wpack<<<8, 256, 0, stream>>>(W1, Wp);
    k_wpack2<<<3, 256, 0, stream>>>(W2, W2p);
    k_hist<<<(EN + 255) / 256, 256, 0, stream>>>(ei, E, N, cnt, rank);
    k_scan_part<<<nb, 256, 0, stream>>>(cnt, N, psum);
    k_scan_mid<<<1, 256, 0, stream>>>(psum, nb);
    k_scan_add<<<nb, 256, 0, stream>>>(cnt, N, psum, rowptr);
    k_scatter<<<(EN + 255) / 256, 256, 0, stream>>>(ei, E, N, rowptr, rank, col);

    k_gemm1<<<(N + 63) / 64, 256, 0, stream>>>(x, Wp, as1, ad1,
                                               (unsigned short*)h1A, (unsigned short*)h1Bp,
                                               a_src1, a_dst1, N);
    int nag = (N + 7) / 8;
    k_aggr1<<<nag, 256, 0, stream>>>(rowptr, cnt, col, a_src1, a_dst1, h1A, b1, out1h, out1l, N, 0);
    k_aggr1<<<nag, 256, 0, stream>>>(rowptr, cnt, col, a_src1, a_dst1, h1Bp, b1, out1h, out1l, N, 1);
    k_gemm2<<<(N + 63) / 64, 256, 0, stream>>>(out1h, out1l, W2p, as2, ad2,
                                               (unsigned short*)h2b, a_src2v, a_dst2v, N);
    k_aggr2<<<nag, 256, 0, stream>>>(rowptr, cnt, col, a_src2v, a_dst2v, h2b, b2, (float*)d_out, N);
}